// Round 4
// baseline (690.032 us; speedup 1.0000x reference)
//
#include <hip/hip_runtime.h>
#include <cstdint>
#include <cstddef>

// ---------------------------------------------------------------------------
// Episodic memory module (DMN) on MI355X — round 11.
//
// R10 post-mortem: rkh->LDS gained only 4us (re-loads were L2-resident:
// FETCH unchanged); staging writes at 256B inter-lane stride caused 938K
// bank conflicts.  scan remains latency/LDS-bound (Occ 10%, 2 waves/SIMD).
// scores launches are tiny-work, latency-dominated kernels whose inputs all
// live in scan's WG already.
//
// R11: (a) fuse per-episode scores into scan epilogue (ep0/ep1 scans):
//         wave w -> col-tile NT=w&3, row-half MTG=w>>2 (16 row-tiles);
//         kt-outer so mem reads = 16 LDS b128/wave; W1 frags in regs;
//         pfix-seeded acc; accumulate via aw_lds (free post-loop) atomics.
//         Kills 2 launches (~68us) for ~+7us/scan of VALU work.
//      (b) rkh staging rewritten stride-1 (dstw[i*512+tid]) — conflict-free.
//      xproj / scores_fixed / prep unchanged.
// ---------------------------------------------------------------------------

typedef __bf16 bf16_t;
typedef __attribute__((ext_vector_type(8))) __bf16 bf16x8;
typedef __attribute__((ext_vector_type(4))) __bf16 bf16x4;
typedef __attribute__((ext_vector_type(4))) float f32x4;

static __device__ __forceinline__ f32x4 mfma16(bf16x8 a, bf16x8 b, f32x4 c) {
  return __builtin_amdgcn_mfma_f32_16x16x32_bf16(a, b, c, 0, 0, 0);
}
static __device__ __forceinline__ float fast_rcp(float x) { return __builtin_amdgcn_rcpf(x); }
static __device__ __forceinline__ float sigmoid_f(float x) {
  return fast_rcp(1.f + exp2f(-1.44269504f * x));
}
static __device__ __forceinline__ float tanh_f(float x) {
  float e = exp2f(2.88539008f * x);
  return 1.f - 2.f * fast_rcp(e + 1.f);
}
static __device__ __forceinline__ unsigned short f2bf(float x) {
  __bf16 h = (__bf16)x;
  return __builtin_bit_cast(unsigned short, h);
}
// Workgroup barrier WITHOUT the vmcnt(0) drain __syncthreads() carries.
// All call sites are in wave-uniform control flow.
static __device__ __forceinline__ void ldsbar() {
  asm volatile("s_waitcnt lgkmcnt(0)\n\ts_barrier" ::: "memory");
}

// ws layout (bf16 element offsets).  B-fragment layout for a K x N matrix:
// elem(k,n) at ((kt*NT + nt)*64 + lane)*8 + j, kt=k/32, nt=n/16,
// lane=((k%32)/8)*16 + (n%16), j=k%8.
static constexpr size_t E_GRUK  = 0;                            // K=256 N=512
static constexpr size_t E_RKR   = 131072;                       // K=256 N=256
static constexpr size_t E_RKH   = 196608;
static constexpr size_t E_W1F   = 262144;                       // K=1024 N=64
static constexpr size_t E_WMF   = 327680;                       // K=768 N=256
static constexpr size_t E_XR    = 524288;                       // + b*131072 (A-frag)
static constexpr size_t E_XHC   = E_XR  + (size_t)128 * 131072; // + b*131072 (C order)
static constexpr size_t E_FACTS = E_XHC + (size_t)128 * 131072; // + b*131072 (A-frag)
static constexpr size_t E_END   = E_FACTS + (size_t)128 * 131072;
static constexpr size_t F_SCORES = 0;
static constexpr size_t F_MEM    = 65536;
static constexpr size_t F_PFIX   = 131072;   // 128*32*4*64 f32x4 = 4M floats

__global__ void prep_weights(const float* __restrict__ gru_k,
                             const float* __restrict__ gru_rk,
                             const float* __restrict__ W1,
                             const float* __restrict__ Wm,
                             bf16_t* __restrict__ ws) {
  size_t idx = (size_t)blockIdx.x * 256 + threadIdx.x;
  if (idx >= 524288) return;
  size_t local; int NT, which;
  if (idx < 131072)      { local = idx;          NT = 32; which = 0; }
  else if (idx < 196608) { local = idx - 131072; NT = 16; which = 1; }
  else if (idx < 262144) { local = idx - 196608; NT = 16; which = 2; }
  else if (idx < 327680) { local = idx - 262144; NT = 4;  which = 3; }
  else                   { local = idx - 327680; NT = 16; which = 4; }
  int j    = (int)(local & 7);
  int lane = (int)((local >> 3) & 63);
  size_t rem = local >> 9;
  int nt = (int)(rem % NT);
  int kt = (int)(rem / NT);
  int k = kt * 32 + (lane >> 4) * 8 + j;
  int n = nt * 16 + (lane & 15);
  float v;
  switch (which) {
    case 0:  v = gru_k[(size_t)k * 768 + 256 + n]; break;
    case 1:  v = gru_rk[(size_t)k * 768 + 256 + n]; break;
    case 2:  v = gru_rk[(size_t)k * 768 + 512 + n]; break;
    case 3:  v = (n < 50) ? W1[(size_t)k * 50 + n] : 0.f; break;
    default: v = Wm[(size_t)k * 256 + n]; break;
  }
  ws[idx] = (__bf16)v;
}

// ------------------------------- kernel A ----------------------------------
// x_proj = facts[b] @ gru_k[:,U:3U] + bias; also persists facts bf16 A-frags.
// grid (b=128, s=8), 512 threads (8 waves, nt=4/wave).  WG does Mt in
// [4s,4s+4) as 2 pair-iterations; each gk fragment feeds 2 A-tiles.
// (512,4): R8-proven config — VGPR 64, no spills, 66us.  (512,8) spilled.
__global__ __launch_bounds__(512, 4)
void xproj_kernel(const float* __restrict__ facts,
                  const float* __restrict__ question,
                  const float* __restrict__ gru_bg,
                  bf16_t* __restrict__ ws,
                  float* __restrict__ mem_ws) {
  const int b = blockIdx.x, s = blockIdx.y;
  const int tid = threadIdx.x, w = tid >> 6, lane = tid & 63;
  const int quad = lane >> 4, col = lane & 15;
  __shared__ float grub[512];
  __shared__ bf16_t fragbuf[8192];   // 2 tiles; logical unit u at u^kt (swizzled)
  __shared__ bf16_t xrtrans[8192];   // 2 tiles; logical unit u at u^((u>>4)&3)
  grub[tid] = gru_bg[256 + tid];     // [0,256)=xr bias, [256,512)=xh bias
  if (s == 0 && tid < 256) mem_ws[b * 256 + tid] = question[(size_t)b * 256 + tid];
  __syncthreads();

  bf16_t* xr_ws = ws + E_XR   + (size_t)b * 131072;
  bf16_t* xh_ws = ws + E_XHC  + (size_t)b * 131072;
  bf16_t* ff_ws = ws + E_FACTS + (size_t)b * 131072;
  const bf16_t* gbase = ws + E_GRUK;
  // staging ownership: 512 threads cover 2 tiles x 16 rows x 16 col-segs
  const int tile = tid >> 8, row = (tid >> 4) & 15, cseg = tid & 15;

  // this thread's two swizzled fragbuf deposit units (constant across iters)
  int wunit[2];
  #pragma unroll
  for (int half = 0; half < 2; ++half) {
    int u0 = cseg * 16 + half * 8;
    int kt = u0 >> 5, qk = (u0 >> 3) & 3;
    int u = kt * 64 + qk * 16 + row;
    wunit[half] = tile * 512 + (u ^ kt);
  }

  for (int it = 0; it < 2; ++it) {
    const int Mt0 = s * 4 + 2 * it;
    // stage this thread's 16 facts floats (one tile each; 512 thr = 2 tiles)
    float v[16];
    {
      const float* src = facts + (((size_t)b * 512) + (Mt0 + tile) * 16 + row) * 256 + cseg * 16;
      #pragma unroll
      for (int i = 0; i < 4; ++i) {
        f32x4 t4 = ((const f32x4*)src)[i];
        v[4*i] = t4[0]; v[4*i+1] = t4[1]; v[4*i+2] = t4[2]; v[4*i+3] = t4[3];
      }
    }
    #pragma unroll
    for (int half = 0; half < 2; ++half) {
      bf16x8 pk;
      #pragma unroll
      for (int j = 0; j < 8; ++j) pk[j] = (__bf16)v[half * 8 + j];
      *(bf16x8*)&fragbuf[wunit[half] * 8] = pk;
    }
    ldsbar();  // bar1: fragbuf visible
    { // persist facts frags for scores (unswizzle -> ws holds logical layout)
      #pragma unroll
      for (int e = 0; e < 2; ++e) {
        int p = 2 * tid + e;
        int t = p >> 9, pu = p & 511;
        int qu = pu ^ (pu >> 6);
        bf16x8 f = *(bf16x8*)&fragbuf[(t * 512 + qu) * 8];
        *(bf16x8*)(ff_ws + (size_t)(Mt0 + t) * 4096 + (size_t)pu * 8) = f;
      }
    }
    // paired MFMA: each gk fragment load feeds BOTH A-tiles; wave owns nt=4
    f32x4 acc[2][4];
    #pragma unroll
    for (int t = 0; t < 2; ++t)
      #pragma unroll
      for (int nt = 0; nt < 4; ++nt) acc[t][nt] = (f32x4){0.f, 0.f, 0.f, 0.f};
    #pragma unroll
    for (int kt = 0; kt < 8; ++kt) {
      int us = (kt * 64 + lane) ^ kt;
      bf16x8 af0 = *(const bf16x8*)&fragbuf[(size_t)us * 8];
      bf16x8 af1 = *(const bf16x8*)&fragbuf[(size_t)(512 + us) * 8];
      #pragma unroll
      for (int nt = 0; nt < 4; ++nt) {
        bf16x8 g = *(const bf16x8*)(gbase + (((size_t)kt * 32 + (w * 4 + nt)) * 64 + lane) * 8);
        acc[0][nt] = mfma16(af0, g, acc[0][nt]);
        acc[1][nt] = mfma16(af1, g, acc[1][nt]);
      }
    }
    // epilogue: waves 0-3 -> xr (transpose via swizzled LDS), 4-7 -> xh
    #pragma unroll
    for (int t = 0; t < 2; ++t)
      #pragma unroll
      for (int nt = 0; nt < 4; ++nt) {
        int o = w * 64 + nt * 16 + col;
        float bias = grub[o];
        if (o < 256) { // wave-uniform: w < 4
          int ktA = o >> 5, qkA = (o >> 3) & 3, j = o & 7;
          #pragma unroll
          for (int r = 0; r < 4; ++r) {
            int u = ktA * 64 + qkA * 16 + (quad * 4 + r);
            int us2 = u ^ ((u >> 4) & 3);
            xrtrans[(t * 512 + us2) * 8 + j] = (__bf16)(acc[t][nt][r] + bias);
          }
        } else {       // wave-uniform: w >= 4
          int ntx = (o >> 4) - 16;
          unsigned short s0 = f2bf(acc[t][nt][0] + bias), s1 = f2bf(acc[t][nt][1] + bias);
          unsigned short s2 = f2bf(acc[t][nt][2] + bias), s3 = f2bf(acc[t][nt][3] + bias);
          uint2 pv;
          pv.x = (unsigned)s0 | ((unsigned)s1 << 16);
          pv.y = (unsigned)s2 | ((unsigned)s3 << 16);
          *(uint2*)(xh_ws + ((size_t)(Mt0 + t) * 16 + ntx) * 256 + lane * 4) = pv;
        }
      }
    ldsbar();  // bar2: xrtrans visible
    { // xr store: read swizzled, write logical (ws layout unchanged for scan)
      #pragma unroll
      for (int e = 0; e < 2; ++e) {
        int p = 2 * tid + e;
        int t = p >> 9, pu = p & 511;
        int qu = pu ^ ((pu >> 4) & 3);
        bf16x8 f = *(bf16x8*)&xrtrans[(t * 512 + qu) * 8];
        *(bf16x8*)(xr_ws + (size_t)(Mt0 + t) * 4096 + (size_t)pu * 8) = f;
      }
    }
    // no bar3: next iteration's bar1 orders xrtrans reads vs next writes.
  }
}

// ---------------------------- kernel B0 (once) -----------------------------
// P_fixed = (f.q)@W1[0:256] + |f-q|@W1[512:768] + b1 for all (b, n, h),
// AND episode-0 scores.  At ep0 mem==question, so the m-term A-fragments
// equal the q-term fragments: full ep0 score = (accq + b1) + accm with
// accm = a0@W1b + a2@W1d — 2 extra MFMAs/tile, zero extra VALU build.
// pfix stored in C-frag order (f32x4/lane) as the later-episode acc init.
__global__ __launch_bounds__(256)
void scores_fixed_kernel(const float* __restrict__ question,
                         const float* __restrict__ b1g,
                         const float* __restrict__ W2g,
                         const float* __restrict__ b2g,
                         const bf16_t* __restrict__ ws,
                         float* __restrict__ pfix,
                         float* __restrict__ scores_ws) {
  const int b = blockIdx.x, s = blockIdx.y;
  const int tid = threadIdx.x, w = tid >> 6, lane = tid & 63;
  const int quad = lane >> 4, col = lane & 15;
  __shared__ float q_lds[256], b1_lds[64], W2_lds[64], score_lds[64];
  __shared__ float b2s;
  q_lds[tid] = question[(size_t)b * 256 + tid];
  if (tid < 64) {
    b1_lds[tid] = (tid < 50) ? b1g[tid] : 0.f;
    W2_lds[tid] = (tid < 50) ? W2g[tid] : 0.f;
  }
  if (tid == 0) b2s = b2g[0];
  __syncthreads();
  if (tid < 64) score_lds[tid] = b2s;
  __syncthreads();

  const bf16_t* ffb = ws + E_FACTS + (size_t)b * 131072 + (size_t)s * 4 * 4096;
  const bf16_t* w1b = ws + E_W1F;

  f32x4 accq[4], accm[4];
  #pragma unroll
  for (int mt = 0; mt < 4; ++mt) {
    accq[mt] = (f32x4){0.f, 0.f, 0.f, 0.f};
    accm[mt] = (f32x4){0.f, 0.f, 0.f, 0.f};
  }

  #pragma unroll 2
  for (int kt = 0; kt < 8; ++kt) {
    bf16x8 wf0 = *(const bf16x8*)(w1b + (((size_t)(kt)      * 4 + w) * 64 + lane) * 8);
    bf16x8 wf1 = *(const bf16x8*)(w1b + (((size_t)(8  + kt) * 4 + w) * 64 + lane) * 8);
    bf16x8 wf2 = *(const bf16x8*)(w1b + (((size_t)(16 + kt) * 4 + w) * 64 + lane) * 8);
    bf16x8 wf3 = *(const bf16x8*)(w1b + (((size_t)(24 + kt) * 4 + w) * 64 + lane) * 8);
    const f32x4* qp = (const f32x4*)&q_lds[kt * 32 + quad * 8];
    f32x4 qa = qp[0], qb = qp[1];
    float qv[8] = {qa[0],qa[1],qa[2],qa[3],qb[0],qb[1],qb[2],qb[3]};
    #pragma unroll
    for (int mt = 0; mt < 4; ++mt) {
      bf16x8 f8 = *(const bf16x8*)(ffb + (size_t)mt * 4096 + (kt * 64 + lane) * 8);
      bf16x8 a0, a2;
      #pragma unroll
      for (int j = 0; j < 8; ++j) {
        float fu = (float)f8[j];
        a0[j] = (__bf16)(fu * qv[j]);
        a2[j] = (__bf16)fabsf(fu - qv[j]);
      }
      accq[mt] = mfma16(a0, wf0, accq[mt]);
      accq[mt] = mfma16(a2, wf2, accq[mt]);
      accm[mt] = mfma16(a0, wf1, accm[mt]);
      accm[mt] = mfma16(a2, wf3, accm[mt]);
    }
  }
  int hcol = w * 16 + col;
  float pb1 = b1_lds[hcol], pw2 = W2_lds[hcol];
  f32x4* po = (f32x4*)pfix;
  #pragma unroll
  for (int mt = 0; mt < 4; ++mt) {
    // pfix = q-terms + b1 (the later-episode accumulator seed)
    f32x4 o = accq[mt];
    #pragma unroll
    for (int r = 0; r < 4; ++r) o[r] += pb1;
    po[(((size_t)b * 32 + s * 4 + mt) * 4 + w) * 64 + lane] = o;
    // ep0 score partial: tanh(pfix + m-terms) * W2  (mem==q at ep0)
    float p[4];
    #pragma unroll
    for (int r = 0; r < 4; ++r) p[r] = tanh_f(o[r] + accm[mt][r]) * pw2;
    #pragma unroll
    for (int r = 0; r < 4; ++r) {
      p[r] += __shfl_xor(p[r], 1, 64);
      p[r] += __shfl_xor(p[r], 2, 64);
      p[r] += __shfl_xor(p[r], 4, 64);
      p[r] += __shfl_xor(p[r], 8, 64);
    }
    if (col == 0) {
      #pragma unroll
      for (int r = 0; r < 4; ++r)
        atomicAdd(&score_lds[mt * 16 + quad * 4 + r], p[r]);
    }
  }
  __syncthreads();
  if (tid < 64) scores_ws[(size_t)b * 512 + s * 64 + tid] = score_lds[tid];
}

// ------------------------------- kernel C ----------------------------------
// softmax + chunked-Picard attn-GRU scan (T=32, 16 chunks) + memory update
// + (ep0/ep1) fused next-episode scores.
// 128 WGs x 512 threads.  2 barriers/chunk; h lives in LDS as bf16 A-frag
// source (broadcast ds_read_b128); exact fp32 self-term in registers.
// R11: fused scores epilogue — wave w: col-tile NT=w&3, row-half MTG=w>>2,
// 16 row-tiles; kt-outer so mem LDS reads = 16 b128/wave; W1 frags in regs;
// acc seeded from pfix; accumulate into aw_lds (free after main loop).
__global__ __launch_bounds__(512, 1)
void scan_kernel(const float* __restrict__ question,
                 const float* __restrict__ bmg,
                 const float* __restrict__ W2g,
                 const float* __restrict__ b2g,
                 const bf16_t* __restrict__ ws,
                 float* __restrict__ scores_ws,
                 float* __restrict__ mem_ws,
                 const float* __restrict__ pfix,
                 float* __restrict__ out,
                 int last) {
  const int b = blockIdx.x;
  const int tid = threadIdx.x, w = tid >> 6, lane = tid & 63;
  const int quad = lane >> 4, col = lane & 15;
  const int do_scores = !last;

  __shared__ bf16_t hb_lds[512];        // bf16 h ping-pong [0,256) / [256,512)
  __shared__ float aw_lds[512], pt_lds[16];
  __shared__ float q_lds[256], mem_lds[256], bm_lds[256], red[16];
  __shared__ float W2_lds[64];
  __shared__ float b2sh;
  __shared__ bf16_t fragbuf[8192];      // rh A-frags, 2 M-tiles x 4096
  __shared__ bf16_t rkh_lds[65536];     // rkh B-frags, 128KB, staged once

  // stage rkh frags global->LDS, stride-1 per lane (conflict-free, coalesced)
  {
    const bf16x8* srcw = (const bf16x8*)(ws + E_RKH);
    bf16x8* dstw = (bf16x8*)rkh_lds;
    #pragma unroll
    for (int i = 0; i < 16; ++i)
      dstw[(size_t)i * 512 + tid] = srcw[(size_t)i * 512 + tid];
  }

  if (tid < 256) {
    q_lds[tid]   = question[(size_t)b * 256 + tid];
    mem_lds[tid] = mem_ws[(size_t)b * 256 + tid];
    bm_lds[tid]  = bmg[tid];
  }
  if (tid < 64) W2_lds[tid] = (tid < 50) ? W2g[tid] : 0.f;
  if (tid == 0) b2sh = b2g[0];
  hb_lds[tid] = (__bf16)0.f;
  // softmax over 512 scores (1/thread)
  float s0 = scores_ws[(size_t)b * 512 + tid];
  float mx = s0;
  #pragma unroll
  for (int o = 32; o > 0; o >>= 1) mx = fmaxf(mx, __shfl_xor(mx, o, 64));
  if (lane == 0) red[w] = mx;
  __syncthreads();
  float gmax = red[0];
  #pragma unroll
  for (int i = 1; i < 8; ++i) gmax = fmaxf(gmax, red[i]);
  float e0 = __expf(s0 - gmax);
  float sm = e0;
  #pragma unroll
  for (int o = 32; o > 0; o >>= 1) sm += __shfl_xor(sm, o, 64);
  if (lane == 0) red[8 + w] = sm;
  __syncthreads();
  float tot = red[8];
  #pragma unroll
  for (int i = 9; i < 16; ++i) tot += red[i];
  aw_lds[tid] = e0 * fast_rcp(tot);
  ldsbar();
  // per-chunk (T=32) blend weights in place:
  // aw[s] := a_s * prod_{j>s in chunk}(1-a_j),  pt[ct] := prod(1-a) over chunk
  if (tid < 16) {
    float av[32];
    #pragma unroll
    for (int j = 0; j < 32; ++j) av[j] = aw_lds[tid * 32 + j];
    float suf = 1.f;
    #pragma unroll
    for (int j = 31; j >= 0; --j) {
      aw_lds[tid * 32 + j] = av[j] * suf;
      suf *= (1.f - av[j]);
    }
    pt_lds[tid] = suf;
  }
  ldsbar();  // also covers rkh_lds staging visibility (lgkmcnt drains ds_writes)

  // S1 recurrence weights: wave w owns out cols [32w, 32w+32); regs (64 VGPR)
  const bf16_t* xrb = ws + E_XR  + (size_t)b * 131072;
  const bf16_t* xhb = ws + E_XHC + (size_t)b * 131072;
  bf16x8 fr[2][8];
  {
    const bf16_t* rb = ws + E_RKR;
    #pragma unroll
    for (int nt = 0; nt < 2; ++nt)
      #pragma unroll
      for (int kt = 0; kt < 8; ++kt) {
        size_t off = (((size_t)kt * 16 + (w * 2 + nt)) * 64 + lane) * 8;
        fr[nt][kt] = *(const bf16x8*)(rb + off);
      }
  }
  // chunk-0 xr (A-frag, kt=w, 2 M-tiles) and xh (C order, 2 nt x 2 Mt)
  bf16x8 xf_c[2];
  bf16x4 xh_c[2][2];
  #pragma unroll
  for (int mt = 0; mt < 2; ++mt) {
    xf_c[mt] = *(const bf16x8*)(xrb + (size_t)mt * 4096 + ((size_t)w * 64 + lane) * 8);
    #pragma unroll
    for (int nt = 0; nt < 2; ++nt)
      xh_c[mt][nt] = *(const bf16x4*)(xhb + ((size_t)mt * 16 + w * 2 + nt) * 256 + lane * 4);
  }

  bf16_t* hbc = &hb_lds[0];
  bf16_t* hbn = &hb_lds[256];
  float hs0 = 0.f, hs1 = 0.f;  // exact fp32 self-copy of wave's own h cols

  for (int ct = 0; ct < 16; ++ct) {
    // S1: rv0 = h @ rkr.  h read as bf16 A-frag via broadcast ds_read_b128.
    // Split-K: 2 chains of 4 per acc.
    f32x4 z = (f32x4){0.f,0.f,0.f,0.f};
    f32x4 a0a = z, a0b = z, a1a = z, a1b = z;
    #pragma unroll
    for (int kt = 0; kt < 4; ++kt) {
      bf16x8 hf = *(const bf16x8*)&hbc[kt * 32 + quad * 8];
      a0a = mfma16(hf, fr[0][kt], a0a);
      a1a = mfma16(hf, fr[1][kt], a1a);
    }
    #pragma unroll
    for (int kt = 4; kt < 8; ++kt) {
      bf16x8 hf = *(const bf16x8*)&hbc[kt * 32 + quad * 8];
      a0b = mfma16(hf, fr[0][kt], a0b);
      a1b = mfma16(hf, fr[1][kt], a1b);
    }
    f32x4 ac0 = a0a + a0b, ac1 = a1a + a1b;
    // rv via intra-wave shuffles (producing wave == consuming wave):
    float rv[8];
    #pragma unroll
    for (int j = 0; j < 8; ++j) {
      int c = quad * 8 + j;
      float v0 = __shfl(ac0[0], c & 15, 64);
      float v1 = __shfl(ac1[0], c & 15, 64);
      rv[j] = (c < 16) ? v0 : v1;
    }
    // S2: rh A-frags (kt=w) for both M-tiles
    {
      bf16x8 aW = *(const bf16x8*)&hbc[w * 32 + quad * 8];
      #pragma unroll
      for (int mt = 0; mt < 2; ++mt) {
        bf16x8 rh;
        #pragma unroll
        for (int j = 0; j < 8; ++j)
          rh[j] = (__bf16)(sigmoid_f((float)xf_c[mt][j] + rv[j]) * (float)aW[j]);
        *(bf16x8*)&fragbuf[mt * 4096 + (w * 64 + lane) * 8] = rh;
      }
    }
    ldsbar();  // barrier 1: fragbuf visible
    // prefetch next chunk's xr/xh (distance 1; consumed next iteration)
    bf16x8 xf_n[2];
    bf16x4 xh_n[2][2];
    {
      int ctn = (ct + 1) & 15;
      #pragma unroll
      for (int mt = 0; mt < 2; ++mt) {
        xf_n[mt] = *(const bf16x8*)(xrb + (size_t)(2 * ctn + mt) * 4096 + ((size_t)w * 64 + lane) * 8);
        #pragma unroll
        for (int nt = 0; nt < 2; ++nt)
          xh_n[mt][nt] = *(const bf16x4*)(xhb + ((size_t)(2 * ctn + mt) * 16 + w * 2 + nt) * 256 + lane * 4);
      }
    }
    // S3: HH = rh @ rkh  (weights from LDS; kt outer so each frag read once)
    f32x4 aH[2][2];
    #pragma unroll
    for (int mt = 0; mt < 2; ++mt) { aH[mt][0] = z; aH[mt][1] = z; }
    #pragma unroll
    for (int kt = 0; kt < 8; ++kt) {
      bf16x8 f0 = *(const bf16x8*)&rkh_lds[(((size_t)kt * 16 + w * 2)     * 64 + lane) * 8];
      bf16x8 f1 = *(const bf16x8*)&rkh_lds[(((size_t)kt * 16 + w * 2 + 1) * 64 + lane) * 8];
      #pragma unroll
      for (int mt = 0; mt < 2; ++mt) {
        bf16x8 a = *(const bf16x8*)&fragbuf[mt * 4096 + (kt * 64 + lane) * 8];
        aH[mt][0] = mfma16(a, f0, aH[mt][0]);
        aH[mt][1] = mfma16(a, f1, aH[mt][1]);
      }
    }
    // blend over 32 steps: h_end = pt*h + sum_s aw[s]*tanh(xh+HH)[s]
    const float* awp = &aw_lds[ct * 32];
    f32x4 wq0 = *(const f32x4*)&awp[quad * 4];
    f32x4 wq1 = *(const f32x4*)&awp[16 + quad * 4];
    float Pt = pt_lds[ct];
    float part0 = 0.f, part1 = 0.f;
    #pragma unroll
    for (int r = 0; r < 4; ++r) {
      part0 += wq0[r] * tanh_f((float)xh_c[0][0][r] + aH[0][0][r]);
      part1 += wq0[r] * tanh_f((float)xh_c[0][1][r] + aH[0][1][r]);
      part0 += wq1[r] * tanh_f((float)xh_c[1][0][r] + aH[1][0][r]);
      part1 += wq1[r] * tanh_f((float)xh_c[1][1][r] + aH[1][1][r]);
    }
    part0 += __shfl_xor(part0, 16, 64); part0 += __shfl_xor(part0, 32, 64);
    part1 += __shfl_xor(part1, 16, 64); part1 += __shfl_xor(part1, 32, 64);
    float hn0 = Pt * hs0 + part0;
    float hn1 = Pt * hs1 + part1;
    hs0 = hn0; hs1 = hn1;
    if (quad == 0) {       // ping-pong write (bf16) — target not being read
      hbn[w * 32 + col]      = (__bf16)hn0;
      hbn[w * 32 + 16 + col] = (__bf16)hn1;
    }
    ldsbar();  // barrier 2: new h visible; fragbuf free
    { bf16_t* t = hbc; hbc = hbn; hbn = t; }
    #pragma unroll
    for (int mt = 0; mt < 2; ++mt) {
      xf_c[mt] = xf_n[mt];
      xh_c[mt][0] = xh_n[mt][0];
      xh_c[mt][1] = xh_n[mt][1];
    }
  }
  // hbc now holds the episode vector (bf16)

  // phase D: memory = relu([mem, episode, q] @ Wm + bm)
  float r0, r1;
  {
    f32x4 am0 = (f32x4){0.f,0.f,0.f,0.f}, am1 = am0;
    const bf16_t* wmb = ws + E_WMF;
    #pragma unroll
    for (int kt = 0; kt < 24; ++kt) {
      bf16x8 a;
      if (kt >= 8 && kt < 16) {           // episode: already bf16, broadcast read
        a = *(const bf16x8*)&hbc[(kt - 8) * 32 + quad * 8];
      } else {
        const float* sv = (kt < 8) ? &mem_lds[kt * 32] : &q_lds[(kt - 16) * 32];
        const f32x4* vp = (const f32x4*)&sv[quad * 8];
        f32x4 va = vp[0], vb = vp[1];
        #pragma unroll
        for (int j = 0; j < 4; ++j) { a[j] = (__bf16)va[j]; a[4 + j] = (__bf16)vb[j]; }
      }
      bf16x8 b0 = *(const bf16x8*)(wmb + (((size_t)kt * 16 + w * 2)     * 64 + lane) * 8);
      bf16x8 b1 = *(const bf16x8*)(wmb + (((size_t)kt * 16 + w * 2 + 1) * 64 + lane) * 8);
      am0 = mfma16(a, b0, am0);
      am1 = mfma16(a, b1, am1);
    }
    int v0 = w * 32 + col, v1 = w * 32 + 16 + col;
    r0 = fmaxf(am0[0] + bm_lds[v0], 0.f);
    r1 = fmaxf(am1[0] + bm_lds[v1], 0.f);
    if (quad == 0) {
      mem_ws[(size_t)b * 256 + v0] = r0;
      mem_ws[(size_t)b * 256 + v1] = r1;
      if (last) {
        out[(size_t)b * 256 + v0] = r0;
        out[(size_t)b * 256 + v1] = r1;
      }
    }
  }

  // fused next-episode scores (ep0/ep1): scores = b2 + sum_h tanh(pfix+M)*W2
  if (do_scores) {
    ldsbar();                       // all phase-D mem_lds/hbc reads done
    if (quad == 0) {                // publish NEW memory into mem_lds
      mem_lds[w * 32 + col]      = r0;
      mem_lds[w * 32 + 16 + col] = r1;
    }
    aw_lds[tid] = b2sh;             // score accumulator (aw free post-loop)
    ldsbar();

    const int NT = w & 3, MTG = w >> 2;
    const bf16_t* w1b = ws + E_W1F;
    const bf16_t* ffb = ws + E_FACTS + (size_t)b * 131072 + (size_t)MTG * 16 * 4096;
    const f32x4* pf = (const f32x4*)pfix;

    bf16x8 wf1[8], wf3[8];
    #pragma unroll
    for (int kt = 0; kt < 8; ++kt) {
      wf1[kt] = *(const bf16x8*)(w1b + (((size_t)(8  + kt) * 4 + NT) * 64 + lane) * 8);
      wf3[kt] = *(const bf16x8*)(w1b + (((size_t)(24 + kt) * 4 + NT) * 64 + lane) * 8);
    }
    f32x4 sacc[16];
    #pragma unroll
    for (int i = 0; i < 16; ++i)
      sacc[i] = pf[(((size_t)b * 32 + MTG * 16 + i) * 4 + NT) * 64 + lane];

    #pragma unroll 2
    for (int kt = 0; kt < 8; ++kt) {
      const f32x4* mp = (const f32x4*)&mem_lds[kt * 32 + quad * 8];
      f32x4 ma = mp[0], mb = mp[1];
      float mv[8] = {ma[0],ma[1],ma[2],ma[3],mb[0],mb[1],mb[2],mb[3]};
      #pragma unroll
      for (int i = 0; i < 16; ++i) {
        bf16x8 f8 = *(const bf16x8*)(ffb + (size_t)i * 4096 + (kt * 64 + lane) * 8);
        bf16x8 a1, a3;
        #pragma unroll
        for (int j = 0; j < 8; ++j) {
          float fu = (float)f8[j];
          a1[j] = (__bf16)(fu * mv[j]);
          a3[j] = (__bf16)fabsf(fu - mv[j]);
        }
        sacc[i] = mfma16(a1, wf1[kt], sacc[i]);
        sacc[i] = mfma16(a3, wf3[kt], sacc[i]);
      }
    }
    float pw2 = W2_lds[NT * 16 + col];
    #pragma unroll
    for (int i = 0; i < 16; ++i) {
      float p[4];
      #pragma unroll
      for (int r = 0; r < 4; ++r) p[r] = tanh_f(sacc[i][r]) * pw2;
      #pragma unroll
      for (int r = 0; r < 4; ++r) {
        p[r] += __shfl_xor(p[r], 1, 64);
        p[r] += __shfl_xor(p[r], 2, 64);
        p[r] += __shfl_xor(p[r], 4, 64);
        p[r] += __shfl_xor(p[r], 8, 64);
      }
      if (col == 0) {
        #pragma unroll
        for (int r = 0; r < 4; ++r)
          atomicAdd(&aw_lds[(MTG * 16 + i) * 16 + quad * 4 + r], p[r]);
      }
    }
    ldsbar();
    scores_ws[(size_t)b * 512 + tid] = aw_lds[tid];
  }
}

extern "C" void kernel_launch(void* const* d_in, const int* in_sizes, int n_in,
                              void* d_out, int out_size, void* d_ws, size_t ws_size,
                              hipStream_t stream) {
  (void)in_sizes; (void)n_in; (void)out_size; (void)ws_size;
  const float* facts    = (const float*)d_in[0];
  const float* question = (const float*)d_in[1];
  const float* W1       = (const float*)d_in[2];
  const float* b1       = (const float*)d_in[3];
  const float* W2       = (const float*)d_in[4];
  const float* b2       = (const float*)d_in[5];
  const float* gru_k    = (const float*)d_in[6];
  const float* gru_rk   = (const float*)d_in[7];
  const float* gru_b    = (const float*)d_in[8];
  const float* Wm       = (const float*)d_in[9];
  const float* bm       = (const float*)d_in[10];
  bf16_t* ws = (bf16_t*)d_ws;
  float* fws = (float*)(ws + E_END);
  float* scores_ws = fws + F_SCORES;
  float* mem_ws    = fws + F_MEM;
  float* pfix_ws   = fws + F_PFIX;
  float* out = (float*)d_out;

  prep_weights<<<2048, 256, 0, stream>>>(gru_k, gru_rk, W1, Wm, ws);
  xproj_kernel<<<dim3(128, 8), 512, 0, stream>>>(facts, question, gru_b, ws, mem_ws);
  // ep0: mem==question, scores come out of the fixed kernel directly
  scores_fixed_kernel<<<dim3(128, 8), 256, 0, stream>>>(question, b1, W2, b2, ws, pfix_ws, scores_ws);
  // scans: ep0/ep1 fuse next-episode scores in their epilogue; ep2 writes out
  scan_kernel<<<128, 512, 0, stream>>>(question, bm, W2, b2, ws, scores_ws, mem_ws, pfix_ws, out, 0);
  scan_kernel<<<128, 512, 0, stream>>>(question, bm, W2, b2, ws, scores_ws, mem_ws, pfix_ws, out, 0);
  scan_kernel<<<128, 512, 0, stream>>>(question, bm, W2, b2, ws, scores_ws, mem_ws, pfix_ws, out, 1);
}

// Round 5
// 449.886 us; speedup vs baseline: 1.5338x; 1.5338x over previous
//
#include <hip/hip_runtime.h>
#include <cstdint>
#include <cstddef>

// ---------------------------------------------------------------------------
// Episodic memory module (DMN) on MI355X — round 12.
//
// R11 post-mortem: fused-scores epilogue spilled — a 512-thread WG (8 waves)
// needs >=2 waves/SIMD resident, so VGPR is HARD-capped at 128 no matter what
// __launch_bounds__ says.  Epilogue live set (wf 64 + sacc[16] 64 + temps)
// blew it: WRITE_SIZE 0.13->17.4MB (scratch), scan 62->235us.  Fusion logic
// itself verified correct (passed, absmax unchanged).
//
// R12: same fusion, register-budgeted: score accumulator chunked 16 -> 4x4
// (#pragma unroll 1 chunk loop; sacc declared inside chunk => live range one
// chunk).  Peak epilogue live ~= wf 64 + sacc 16 + temps ~30 < 128.
// Everything else identical to R11 (incl. stride-1 rkh staging).
// Tripwire for post-mortem: scan WRITE_SIZE must be back at ~0.15MB.
// ---------------------------------------------------------------------------

typedef __bf16 bf16_t;
typedef __attribute__((ext_vector_type(8))) __bf16 bf16x8;
typedef __attribute__((ext_vector_type(4))) __bf16 bf16x4;
typedef __attribute__((ext_vector_type(4))) float f32x4;

static __device__ __forceinline__ f32x4 mfma16(bf16x8 a, bf16x8 b, f32x4 c) {
  return __builtin_amdgcn_mfma_f32_16x16x32_bf16(a, b, c, 0, 0, 0);
}
static __device__ __forceinline__ float fast_rcp(float x) { return __builtin_amdgcn_rcpf(x); }
static __device__ __forceinline__ float sigmoid_f(float x) {
  return fast_rcp(1.f + exp2f(-1.44269504f * x));
}
static __device__ __forceinline__ float tanh_f(float x) {
  float e = exp2f(2.88539008f * x);
  return 1.f - 2.f * fast_rcp(e + 1.f);
}
static __device__ __forceinline__ unsigned short f2bf(float x) {
  __bf16 h = (__bf16)x;
  return __builtin_bit_cast(unsigned short, h);
}
// Workgroup barrier WITHOUT the vmcnt(0) drain __syncthreads() carries.
// All call sites are in wave-uniform control flow.
static __device__ __forceinline__ void ldsbar() {
  asm volatile("s_waitcnt lgkmcnt(0)\n\ts_barrier" ::: "memory");
}

// ws layout (bf16 element offsets).  B-fragment layout for a K x N matrix:
// elem(k,n) at ((kt*NT + nt)*64 + lane)*8 + j, kt=k/32, nt=n/16,
// lane=((k%32)/8)*16 + (n%16), j=k%8.
static constexpr size_t E_GRUK  = 0;                            // K=256 N=512
static constexpr size_t E_RKR   = 131072;                       // K=256 N=256
static constexpr size_t E_RKH   = 196608;
static constexpr size_t E_W1F   = 262144;                       // K=1024 N=64
static constexpr size_t E_WMF   = 327680;                       // K=768 N=256
static constexpr size_t E_XR    = 524288;                       // + b*131072 (A-frag)
static constexpr size_t E_XHC   = E_XR  + (size_t)128 * 131072; // + b*131072 (C order)
static constexpr size_t E_FACTS = E_XHC + (size_t)128 * 131072; // + b*131072 (A-frag)
static constexpr size_t E_END   = E_FACTS + (size_t)128 * 131072;
static constexpr size_t F_SCORES = 0;
static constexpr size_t F_MEM    = 65536;
static constexpr size_t F_PFIX   = 131072;   // 128*32*4*64 f32x4 = 4M floats

__global__ void prep_weights(const float* __restrict__ gru_k,
                             const float* __restrict__ gru_rk,
                             const float* __restrict__ W1,
                             const float* __restrict__ Wm,
                             bf16_t* __restrict__ ws) {
  size_t idx = (size_t)blockIdx.x * 256 + threadIdx.x;
  if (idx >= 524288) return;
  size_t local; int NT, which;
  if (idx < 131072)      { local = idx;          NT = 32; which = 0; }
  else if (idx < 196608) { local = idx - 131072; NT = 16; which = 1; }
  else if (idx < 262144) { local = idx - 196608; NT = 16; which = 2; }
  else if (idx < 327680) { local = idx - 262144; NT = 4;  which = 3; }
  else                   { local = idx - 327680; NT = 16; which = 4; }
  int j    = (int)(local & 7);
  int lane = (int)((local >> 3) & 63);
  size_t rem = local >> 9;
  int nt = (int)(rem % NT);
  int kt = (int)(rem / NT);
  int k = kt * 32 + (lane >> 4) * 8 + j;
  int n = nt * 16 + (lane & 15);
  float v;
  switch (which) {
    case 0:  v = gru_k[(size_t)k * 768 + 256 + n]; break;
    case 1:  v = gru_rk[(size_t)k * 768 + 256 + n]; break;
    case 2:  v = gru_rk[(size_t)k * 768 + 512 + n]; break;
    case 3:  v = (n < 50) ? W1[(size_t)k * 50 + n] : 0.f; break;
    default: v = Wm[(size_t)k * 256 + n]; break;
  }
  ws[idx] = (__bf16)v;
}

// ------------------------------- kernel A ----------------------------------
// x_proj = facts[b] @ gru_k[:,U:3U] + bias; also persists facts bf16 A-frags.
// grid (b=128, s=8), 512 threads (8 waves, nt=4/wave).  WG does Mt in
// [4s,4s+4) as 2 pair-iterations; each gk fragment feeds 2 A-tiles.
// (512,4): R8-proven config — VGPR 64, no spills, 66us.  (512,8) spilled.
__global__ __launch_bounds__(512, 4)
void xproj_kernel(const float* __restrict__ facts,
                  const float* __restrict__ question,
                  const float* __restrict__ gru_bg,
                  bf16_t* __restrict__ ws,
                  float* __restrict__ mem_ws) {
  const int b = blockIdx.x, s = blockIdx.y;
  const int tid = threadIdx.x, w = tid >> 6, lane = tid & 63;
  const int quad = lane >> 4, col = lane & 15;
  __shared__ float grub[512];
  __shared__ bf16_t fragbuf[8192];   // 2 tiles; logical unit u at u^kt (swizzled)
  __shared__ bf16_t xrtrans[8192];   // 2 tiles; logical unit u at u^((u>>4)&3)
  grub[tid] = gru_bg[256 + tid];     // [0,256)=xr bias, [256,512)=xh bias
  if (s == 0 && tid < 256) mem_ws[b * 256 + tid] = question[(size_t)b * 256 + tid];
  __syncthreads();

  bf16_t* xr_ws = ws + E_XR   + (size_t)b * 131072;
  bf16_t* xh_ws = ws + E_XHC  + (size_t)b * 131072;
  bf16_t* ff_ws = ws + E_FACTS + (size_t)b * 131072;
  const bf16_t* gbase = ws + E_GRUK;
  // staging ownership: 512 threads cover 2 tiles x 16 rows x 16 col-segs
  const int tile = tid >> 8, row = (tid >> 4) & 15, cseg = tid & 15;

  // this thread's two swizzled fragbuf deposit units (constant across iters)
  int wunit[2];
  #pragma unroll
  for (int half = 0; half < 2; ++half) {
    int u0 = cseg * 16 + half * 8;
    int kt = u0 >> 5, qk = (u0 >> 3) & 3;
    int u = kt * 64 + qk * 16 + row;
    wunit[half] = tile * 512 + (u ^ kt);
  }

  for (int it = 0; it < 2; ++it) {
    const int Mt0 = s * 4 + 2 * it;
    // stage this thread's 16 facts floats (one tile each; 512 thr = 2 tiles)
    float v[16];
    {
      const float* src = facts + (((size_t)b * 512) + (Mt0 + tile) * 16 + row) * 256 + cseg * 16;
      #pragma unroll
      for (int i = 0; i < 4; ++i) {
        f32x4 t4 = ((const f32x4*)src)[i];
        v[4*i] = t4[0]; v[4*i+1] = t4[1]; v[4*i+2] = t4[2]; v[4*i+3] = t4[3];
      }
    }
    #pragma unroll
    for (int half = 0; half < 2; ++half) {
      bf16x8 pk;
      #pragma unroll
      for (int j = 0; j < 8; ++j) pk[j] = (__bf16)v[half * 8 + j];
      *(bf16x8*)&fragbuf[wunit[half] * 8] = pk;
    }
    ldsbar();  // bar1: fragbuf visible
    { // persist facts frags for scores (unswizzle -> ws holds logical layout)
      #pragma unroll
      for (int e = 0; e < 2; ++e) {
        int p = 2 * tid + e;
        int t = p >> 9, pu = p & 511;
        int qu = pu ^ (pu >> 6);
        bf16x8 f = *(bf16x8*)&fragbuf[(t * 512 + qu) * 8];
        *(bf16x8*)(ff_ws + (size_t)(Mt0 + t) * 4096 + (size_t)pu * 8) = f;
      }
    }
    // paired MFMA: each gk fragment load feeds BOTH A-tiles; wave owns nt=4
    f32x4 acc[2][4];
    #pragma unroll
    for (int t = 0; t < 2; ++t)
      #pragma unroll
      for (int nt = 0; nt < 4; ++nt) acc[t][nt] = (f32x4){0.f, 0.f, 0.f, 0.f};
    #pragma unroll
    for (int kt = 0; kt < 8; ++kt) {
      int us = (kt * 64 + lane) ^ kt;
      bf16x8 af0 = *(const bf16x8*)&fragbuf[(size_t)us * 8];
      bf16x8 af1 = *(const bf16x8*)&fragbuf[(size_t)(512 + us) * 8];
      #pragma unroll
      for (int nt = 0; nt < 4; ++nt) {
        bf16x8 g = *(const bf16x8*)(gbase + (((size_t)kt * 32 + (w * 4 + nt)) * 64 + lane) * 8);
        acc[0][nt] = mfma16(af0, g, acc[0][nt]);
        acc[1][nt] = mfma16(af1, g, acc[1][nt]);
      }
    }
    // epilogue: waves 0-3 -> xr (transpose via swizzled LDS), 4-7 -> xh
    #pragma unroll
    for (int t = 0; t < 2; ++t)
      #pragma unroll
      for (int nt = 0; nt < 4; ++nt) {
        int o = w * 64 + nt * 16 + col;
        float bias = grub[o];
        if (o < 256) { // wave-uniform: w < 4
          int ktA = o >> 5, qkA = (o >> 3) & 3, j = o & 7;
          #pragma unroll
          for (int r = 0; r < 4; ++r) {
            int u = ktA * 64 + qkA * 16 + (quad * 4 + r);
            int us2 = u ^ ((u >> 4) & 3);
            xrtrans[(t * 512 + us2) * 8 + j] = (__bf16)(acc[t][nt][r] + bias);
          }
        } else {       // wave-uniform: w >= 4
          int ntx = (o >> 4) - 16;
          unsigned short s0 = f2bf(acc[t][nt][0] + bias), s1 = f2bf(acc[t][nt][1] + bias);
          unsigned short s2 = f2bf(acc[t][nt][2] + bias), s3 = f2bf(acc[t][nt][3] + bias);
          uint2 pv;
          pv.x = (unsigned)s0 | ((unsigned)s1 << 16);
          pv.y = (unsigned)s2 | ((unsigned)s3 << 16);
          *(uint2*)(xh_ws + ((size_t)(Mt0 + t) * 16 + ntx) * 256 + lane * 4) = pv;
        }
      }
    ldsbar();  // bar2: xrtrans visible
    { // xr store: read swizzled, write logical (ws layout unchanged for scan)
      #pragma unroll
      for (int e = 0; e < 2; ++e) {
        int p = 2 * tid + e;
        int t = p >> 9, pu = p & 511;
        int qu = pu ^ ((pu >> 4) & 3);
        bf16x8 f = *(bf16x8*)&xrtrans[(t * 512 + qu) * 8];
        *(bf16x8*)(xr_ws + (size_t)(Mt0 + t) * 4096 + (size_t)pu * 8) = f;
      }
    }
    // no bar3: next iteration's bar1 orders xrtrans reads vs next writes.
  }
}

// ---------------------------- kernel B0 (once) -----------------------------
// P_fixed = (f.q)@W1[0:256] + |f-q|@W1[512:768] + b1 for all (b, n, h),
// AND episode-0 scores.  At ep0 mem==question, so the m-term A-fragments
// equal the q-term fragments: full ep0 score = (accq + b1) + accm with
// accm = a0@W1b + a2@W1d — 2 extra MFMAs/tile, zero extra VALU build.
// pfix stored in C-frag order (f32x4/lane) as the later-episode acc init.
__global__ __launch_bounds__(256)
void scores_fixed_kernel(const float* __restrict__ question,
                         const float* __restrict__ b1g,
                         const float* __restrict__ W2g,
                         const float* __restrict__ b2g,
                         const bf16_t* __restrict__ ws,
                         float* __restrict__ pfix,
                         float* __restrict__ scores_ws) {
  const int b = blockIdx.x, s = blockIdx.y;
  const int tid = threadIdx.x, w = tid >> 6, lane = tid & 63;
  const int quad = lane >> 4, col = lane & 15;
  __shared__ float q_lds[256], b1_lds[64], W2_lds[64], score_lds[64];
  __shared__ float b2s;
  q_lds[tid] = question[(size_t)b * 256 + tid];
  if (tid < 64) {
    b1_lds[tid] = (tid < 50) ? b1g[tid] : 0.f;
    W2_lds[tid] = (tid < 50) ? W2g[tid] : 0.f;
  }
  if (tid == 0) b2s = b2g[0];
  __syncthreads();
  if (tid < 64) score_lds[tid] = b2s;
  __syncthreads();

  const bf16_t* ffb = ws + E_FACTS + (size_t)b * 131072 + (size_t)s * 4 * 4096;
  const bf16_t* w1b = ws + E_W1F;

  f32x4 accq[4], accm[4];
  #pragma unroll
  for (int mt = 0; mt < 4; ++mt) {
    accq[mt] = (f32x4){0.f, 0.f, 0.f, 0.f};
    accm[mt] = (f32x4){0.f, 0.f, 0.f, 0.f};
  }

  #pragma unroll 2
  for (int kt = 0; kt < 8; ++kt) {
    bf16x8 wf0 = *(const bf16x8*)(w1b + (((size_t)(kt)      * 4 + w) * 64 + lane) * 8);
    bf16x8 wf1 = *(const bf16x8*)(w1b + (((size_t)(8  + kt) * 4 + w) * 64 + lane) * 8);
    bf16x8 wf2 = *(const bf16x8*)(w1b + (((size_t)(16 + kt) * 4 + w) * 64 + lane) * 8);
    bf16x8 wf3 = *(const bf16x8*)(w1b + (((size_t)(24 + kt) * 4 + w) * 64 + lane) * 8);
    const f32x4* qp = (const f32x4*)&q_lds[kt * 32 + quad * 8];
    f32x4 qa = qp[0], qb = qp[1];
    float qv[8] = {qa[0],qa[1],qa[2],qa[3],qb[0],qb[1],qb[2],qb[3]};
    #pragma unroll
    for (int mt = 0; mt < 4; ++mt) {
      bf16x8 f8 = *(const bf16x8*)(ffb + (size_t)mt * 4096 + (kt * 64 + lane) * 8);
      bf16x8 a0, a2;
      #pragma unroll
      for (int j = 0; j < 8; ++j) {
        float fu = (float)f8[j];
        a0[j] = (__bf16)(fu * qv[j]);
        a2[j] = (__bf16)fabsf(fu - qv[j]);
      }
      accq[mt] = mfma16(a0, wf0, accq[mt]);
      accq[mt] = mfma16(a2, wf2, accq[mt]);
      accm[mt] = mfma16(a0, wf1, accm[mt]);
      accm[mt] = mfma16(a2, wf3, accm[mt]);
    }
  }
  int hcol = w * 16 + col;
  float pb1 = b1_lds[hcol], pw2 = W2_lds[hcol];
  f32x4* po = (f32x4*)pfix;
  #pragma unroll
  for (int mt = 0; mt < 4; ++mt) {
    // pfix = q-terms + b1 (the later-episode accumulator seed)
    f32x4 o = accq[mt];
    #pragma unroll
    for (int r = 0; r < 4; ++r) o[r] += pb1;
    po[(((size_t)b * 32 + s * 4 + mt) * 4 + w) * 64 + lane] = o;
    // ep0 score partial: tanh(pfix + m-terms) * W2  (mem==q at ep0)
    float p[4];
    #pragma unroll
    for (int r = 0; r < 4; ++r) p[r] = tanh_f(o[r] + accm[mt][r]) * pw2;
    #pragma unroll
    for (int r = 0; r < 4; ++r) {
      p[r] += __shfl_xor(p[r], 1, 64);
      p[r] += __shfl_xor(p[r], 2, 64);
      p[r] += __shfl_xor(p[r], 4, 64);
      p[r] += __shfl_xor(p[r], 8, 64);
    }
    if (col == 0) {
      #pragma unroll
      for (int r = 0; r < 4; ++r)
        atomicAdd(&score_lds[mt * 16 + quad * 4 + r], p[r]);
    }
  }
  __syncthreads();
  if (tid < 64) scores_ws[(size_t)b * 512 + s * 64 + tid] = score_lds[tid];
}

// ------------------------------- kernel C ----------------------------------
// softmax + chunked-Picard attn-GRU scan (T=32, 16 chunks) + memory update
// + (ep0/ep1) fused next-episode scores.
// 128 WGs x 512 threads.  512-thr WG => VGPR hard cap 128 (2 waves/SIMD).
// R12: fused scores epilogue register-budgeted — 4 chunks x 4 row-tiles,
// sacc declared per-chunk (16 VGPR live), wf1/wf3 preloaded (64 VGPR),
// #pragma unroll 1 on the chunk loop.  Peak ~110 < 128 -> no spills.
__global__ __launch_bounds__(512, 1)
void scan_kernel(const float* __restrict__ question,
                 const float* __restrict__ bmg,
                 const float* __restrict__ W2g,
                 const float* __restrict__ b2g,
                 const bf16_t* __restrict__ ws,
                 float* __restrict__ scores_ws,
                 float* __restrict__ mem_ws,
                 const float* __restrict__ pfix,
                 float* __restrict__ out,
                 int last) {
  const int b = blockIdx.x;
  const int tid = threadIdx.x, w = tid >> 6, lane = tid & 63;
  const int quad = lane >> 4, col = lane & 15;
  const int do_scores = !last;

  __shared__ bf16_t hb_lds[512];        // bf16 h ping-pong [0,256) / [256,512)
  __shared__ float aw_lds[512], pt_lds[16];
  __shared__ float q_lds[256], mem_lds[256], bm_lds[256], red[16];
  __shared__ float W2_lds[64];
  __shared__ float b2sh;
  __shared__ bf16_t fragbuf[8192];      // rh A-frags, 2 M-tiles x 4096
  __shared__ bf16_t rkh_lds[65536];     // rkh B-frags, 128KB, staged once

  // stage rkh frags global->LDS, stride-1 per lane (conflict-free, coalesced)
  {
    const bf16x8* srcw = (const bf16x8*)(ws + E_RKH);
    bf16x8* dstw = (bf16x8*)rkh_lds;
    #pragma unroll
    for (int i = 0; i < 16; ++i)
      dstw[(size_t)i * 512 + tid] = srcw[(size_t)i * 512 + tid];
  }

  if (tid < 256) {
    q_lds[tid]   = question[(size_t)b * 256 + tid];
    mem_lds[tid] = mem_ws[(size_t)b * 256 + tid];
    bm_lds[tid]  = bmg[tid];
  }
  if (tid < 64) W2_lds[tid] = (tid < 50) ? W2g[tid] : 0.f;
  if (tid == 0) b2sh = b2g[0];
  hb_lds[tid] = (__bf16)0.f;
  // softmax over 512 scores (1/thread)
  float s0 = scores_ws[(size_t)b * 512 + tid];
  float mx = s0;
  #pragma unroll
  for (int o = 32; o > 0; o >>= 1) mx = fmaxf(mx, __shfl_xor(mx, o, 64));
  if (lane == 0) red[w] = mx;
  __syncthreads();
  float gmax = red[0];
  #pragma unroll
  for (int i = 1; i < 8; ++i) gmax = fmaxf(gmax, red[i]);
  float e0 = __expf(s0 - gmax);
  float sm = e0;
  #pragma unroll
  for (int o = 32; o > 0; o >>= 1) sm += __shfl_xor(sm, o, 64);
  if (lane == 0) red[8 + w] = sm;
  __syncthreads();
  float tot = red[8];
  #pragma unroll
  for (int i = 9; i < 16; ++i) tot += red[i];
  aw_lds[tid] = e0 * fast_rcp(tot);
  ldsbar();
  // per-chunk (T=32) blend weights in place:
  // aw[s] := a_s * prod_{j>s in chunk}(1-a_j),  pt[ct] := prod(1-a) over chunk
  if (tid < 16) {
    float av[32];
    #pragma unroll
    for (int j = 0; j < 32; ++j) av[j] = aw_lds[tid * 32 + j];
    float suf = 1.f;
    #pragma unroll
    for (int j = 31; j >= 0; --j) {
      aw_lds[tid * 32 + j] = av[j] * suf;
      suf *= (1.f - av[j]);
    }
    pt_lds[tid] = suf;
  }
  ldsbar();  // also covers rkh_lds staging visibility (lgkmcnt drains ds_writes)

  // S1 recurrence weights: wave w owns out cols [32w, 32w+32); regs (64 VGPR)
  const bf16_t* xrb = ws + E_XR  + (size_t)b * 131072;
  const bf16_t* xhb = ws + E_XHC + (size_t)b * 131072;
  bf16x8 fr[2][8];
  {
    const bf16_t* rb = ws + E_RKR;
    #pragma unroll
    for (int nt = 0; nt < 2; ++nt)
      #pragma unroll
      for (int kt = 0; kt < 8; ++kt) {
        size_t off = (((size_t)kt * 16 + (w * 2 + nt)) * 64 + lane) * 8;
        fr[nt][kt] = *(const bf16x8*)(rb + off);
      }
  }
  // chunk-0 xr (A-frag, kt=w, 2 M-tiles) and xh (C order, 2 nt x 2 Mt)
  bf16x8 xf_c[2];
  bf16x4 xh_c[2][2];
  #pragma unroll
  for (int mt = 0; mt < 2; ++mt) {
    xf_c[mt] = *(const bf16x8*)(xrb + (size_t)mt * 4096 + ((size_t)w * 64 + lane) * 8);
    #pragma unroll
    for (int nt = 0; nt < 2; ++nt)
      xh_c[mt][nt] = *(const bf16x4*)(xhb + ((size_t)mt * 16 + w * 2 + nt) * 256 + lane * 4);
  }

  bf16_t* hbc = &hb_lds[0];
  bf16_t* hbn = &hb_lds[256];
  float hs0 = 0.f, hs1 = 0.f;  // exact fp32 self-copy of wave's own h cols

  for (int ct = 0; ct < 16; ++ct) {
    // S1: rv0 = h @ rkr.  h read as bf16 A-frag via broadcast ds_read_b128.
    // Split-K: 2 chains of 4 per acc.
    f32x4 z = (f32x4){0.f,0.f,0.f,0.f};
    f32x4 a0a = z, a0b = z, a1a = z, a1b = z;
    #pragma unroll
    for (int kt = 0; kt < 4; ++kt) {
      bf16x8 hf = *(const bf16x8*)&hbc[kt * 32 + quad * 8];
      a0a = mfma16(hf, fr[0][kt], a0a);
      a1a = mfma16(hf, fr[1][kt], a1a);
    }
    #pragma unroll
    for (int kt = 4; kt < 8; ++kt) {
      bf16x8 hf = *(const bf16x8*)&hbc[kt * 32 + quad * 8];
      a0b = mfma16(hf, fr[0][kt], a0b);
      a1b = mfma16(hf, fr[1][kt], a1b);
    }
    f32x4 ac0 = a0a + a0b, ac1 = a1a + a1b;
    // rv via intra-wave shuffles (producing wave == consuming wave):
    float rv[8];
    #pragma unroll
    for (int j = 0; j < 8; ++j) {
      int c = quad * 8 + j;
      float v0 = __shfl(ac0[0], c & 15, 64);
      float v1 = __shfl(ac1[0], c & 15, 64);
      rv[j] = (c < 16) ? v0 : v1;
    }
    // S2: rh A-frags (kt=w) for both M-tiles
    {
      bf16x8 aW = *(const bf16x8*)&hbc[w * 32 + quad * 8];
      #pragma unroll
      for (int mt = 0; mt < 2; ++mt) {
        bf16x8 rh;
        #pragma unroll
        for (int j = 0; j < 8; ++j)
          rh[j] = (__bf16)(sigmoid_f((float)xf_c[mt][j] + rv[j]) * (float)aW[j]);
        *(bf16x8*)&fragbuf[mt * 4096 + (w * 64 + lane) * 8] = rh;
      }
    }
    ldsbar();  // barrier 1: fragbuf visible
    // prefetch next chunk's xr/xh (distance 1; consumed next iteration)
    bf16x8 xf_n[2];
    bf16x4 xh_n[2][2];
    {
      int ctn = (ct + 1) & 15;
      #pragma unroll
      for (int mt = 0; mt < 2; ++mt) {
        xf_n[mt] = *(const bf16x8*)(xrb + (size_t)(2 * ctn + mt) * 4096 + ((size_t)w * 64 + lane) * 8);
        #pragma unroll
        for (int nt = 0; nt < 2; ++nt)
          xh_n[mt][nt] = *(const bf16x4*)(xhb + ((size_t)(2 * ctn + mt) * 16 + w * 2 + nt) * 256 + lane * 4);
      }
    }
    // S3: HH = rh @ rkh  (weights from LDS; kt outer so each frag read once)
    f32x4 aH[2][2];
    #pragma unroll
    for (int mt = 0; mt < 2; ++mt) { aH[mt][0] = z; aH[mt][1] = z; }
    #pragma unroll
    for (int kt = 0; kt < 8; ++kt) {
      bf16x8 f0 = *(const bf16x8*)&rkh_lds[(((size_t)kt * 16 + w * 2)     * 64 + lane) * 8];
      bf16x8 f1 = *(const bf16x8*)&rkh_lds[(((size_t)kt * 16 + w * 2 + 1) * 64 + lane) * 8];
      #pragma unroll
      for (int mt = 0; mt < 2; ++mt) {
        bf16x8 a = *(const bf16x8*)&fragbuf[mt * 4096 + (kt * 64 + lane) * 8];
        aH[mt][0] = mfma16(a, f0, aH[mt][0]);
        aH[mt][1] = mfma16(a, f1, aH[mt][1]);
      }
    }
    // blend over 32 steps: h_end = pt*h + sum_s aw[s]*tanh(xh+HH)[s]
    const float* awp = &aw_lds[ct * 32];
    f32x4 wq0 = *(const f32x4*)&awp[quad * 4];
    f32x4 wq1 = *(const f32x4*)&awp[16 + quad * 4];
    float Pt = pt_lds[ct];
    float part0 = 0.f, part1 = 0.f;
    #pragma unroll
    for (int r = 0; r < 4; ++r) {
      part0 += wq0[r] * tanh_f((float)xh_c[0][0][r] + aH[0][0][r]);
      part1 += wq0[r] * tanh_f((float)xh_c[0][1][r] + aH[0][1][r]);
      part0 += wq1[r] * tanh_f((float)xh_c[1][0][r] + aH[1][0][r]);
      part1 += wq1[r] * tanh_f((float)xh_c[1][1][r] + aH[1][1][r]);
    }
    part0 += __shfl_xor(part0, 16, 64); part0 += __shfl_xor(part0, 32, 64);
    part1 += __shfl_xor(part1, 16, 64); part1 += __shfl_xor(part1, 32, 64);
    float hn0 = Pt * hs0 + part0;
    float hn1 = Pt * hs1 + part1;
    hs0 = hn0; hs1 = hn1;
    if (quad == 0) {       // ping-pong write (bf16) — target not being read
      hbn[w * 32 + col]      = (__bf16)hn0;
      hbn[w * 32 + 16 + col] = (__bf16)hn1;
    }
    ldsbar();  // barrier 2: new h visible; fragbuf free
    { bf16_t* t = hbc; hbc = hbn; hbn = t; }
    #pragma unroll
    for (int mt = 0; mt < 2; ++mt) {
      xf_c[mt] = xf_n[mt];
      xh_c[mt][0] = xh_n[mt][0];
      xh_c[mt][1] = xh_n[mt][1];
    }
  }
  // hbc now holds the episode vector (bf16)

  // phase D: memory = relu([mem, episode, q] @ Wm + bm)
  float r0, r1;
  {
    f32x4 am0 = (f32x4){0.f,0.f,0.f,0.f}, am1 = am0;
    const bf16_t* wmb = ws + E_WMF;
    #pragma unroll
    for (int kt = 0; kt < 24; ++kt) {
      bf16x8 a;
      if (kt >= 8 && kt < 16) {           // episode: already bf16, broadcast read
        a = *(const bf16x8*)&hbc[(kt - 8) * 32 + quad * 8];
      } else {
        const float* sv = (kt < 8) ? &mem_lds[kt * 32] : &q_lds[(kt - 16) * 32];
        const f32x4* vp = (const f32x4*)&sv[quad * 8];
        f32x4 va = vp[0], vb = vp[1];
        #pragma unroll
        for (int j = 0; j < 4; ++j) { a[j] = (__bf16)va[j]; a[4 + j] = (__bf16)vb[j]; }
      }
      bf16x8 b0 = *(const bf16x8*)(wmb + (((size_t)kt * 16 + w * 2)     * 64 + lane) * 8);
      bf16x8 b1 = *(const bf16x8*)(wmb + (((size_t)kt * 16 + w * 2 + 1) * 64 + lane) * 8);
      am0 = mfma16(a, b0, am0);
      am1 = mfma16(a, b1, am1);
    }
    int v0 = w * 32 + col, v1 = w * 32 + 16 + col;
    r0 = fmaxf(am0[0] + bm_lds[v0], 0.f);
    r1 = fmaxf(am1[0] + bm_lds[v1], 0.f);
    if (quad == 0) {
      mem_ws[(size_t)b * 256 + v0] = r0;
      mem_ws[(size_t)b * 256 + v1] = r1;
      if (last) {
        out[(size_t)b * 256 + v0] = r0;
        out[(size_t)b * 256 + v1] = r1;
      }
    }
  }

  // fused next-episode scores (ep0/ep1): scores = b2 + sum_h tanh(pfix+M)*W2
  // Register-budgeted: 4 chunks x 4 row-tiles; sacc live range = one chunk.
  if (do_scores) {
    ldsbar();                       // all phase-D mem_lds/hbc reads done
    if (quad == 0) {                // publish NEW memory into mem_lds
      mem_lds[w * 32 + col]      = r0;
      mem_lds[w * 32 + 16 + col] = r1;
    }
    aw_lds[tid] = b2sh;             // score accumulator (aw free post-loop)
    ldsbar();

    const int NT = w & 3, MTG = w >> 2;
    const bf16_t* w1b = ws + E_W1F;
    const bf16_t* ffb = ws + E_FACTS + (size_t)b * 131072 + (size_t)MTG * 16 * 4096;
    const f32x4* pf = (const f32x4*)pfix;
    const float pw2 = W2_lds[NT * 16 + col];

    bf16x8 wf1[8], wf3[8];
    #pragma unroll
    for (int kt = 0; kt < 8; ++kt) {
      wf1[kt] = *(const bf16x8*)(w1b + (((size_t)(8  + kt) * 4 + NT) * 64 + lane) * 8);
      wf3[kt] = *(const bf16x8*)(w1b + (((size_t)(24 + kt) * 4 + NT) * 64 + lane) * 8);
    }
    #pragma unroll 1
    for (int c = 0; c < 4; ++c) {
      f32x4 sacc[4];
      #pragma unroll
      for (int i = 0; i < 4; ++i)
        sacc[i] = pf[(((size_t)b * 32 + MTG * 16 + c * 4 + i) * 4 + NT) * 64 + lane];
      #pragma unroll
      for (int kt = 0; kt < 8; ++kt) {
        const f32x4* mp = (const f32x4*)&mem_lds[kt * 32 + quad * 8];
        f32x4 ma = mp[0], mb = mp[1];
        float mv[8] = {ma[0],ma[1],ma[2],ma[3],mb[0],mb[1],mb[2],mb[3]};
        #pragma unroll
        for (int i = 0; i < 4; ++i) {
          bf16x8 f8 = *(const bf16x8*)(ffb + (size_t)(c * 4 + i) * 4096 + (kt * 64 + lane) * 8);
          bf16x8 a1, a3;
          #pragma unroll
          for (int j = 0; j < 8; ++j) {
            float fu = (float)f8[j];
            a1[j] = (__bf16)(fu * mv[j]);
            a3[j] = (__bf16)fabsf(fu - mv[j]);
          }
          sacc[i] = mfma16(a1, wf1[kt], sacc[i]);
          sacc[i] = mfma16(a3, wf3[kt], sacc[i]);
        }
      }
      #pragma unroll
      for (int i = 0; i < 4; ++i) {
        float p[4];
        #pragma unroll
        for (int r = 0; r < 4; ++r) p[r] = tanh_f(sacc[i][r]) * pw2;
        #pragma unroll
        for (int r = 0; r < 4; ++r) {
          p[r] += __shfl_xor(p[r], 1, 64);
          p[r] += __shfl_xor(p[r], 2, 64);
          p[r] += __shfl_xor(p[r], 4, 64);
          p[r] += __shfl_xor(p[r], 8, 64);
        }
        if (col == 0) {
          #pragma unroll
          for (int r = 0; r < 4; ++r)
            atomicAdd(&aw_lds[(MTG * 16 + c * 4 + i) * 16 + quad * 4 + r], p[r]);
        }
      }
    }
    ldsbar();
    scores_ws[(size_t)b * 512 + tid] = aw_lds[tid];
  }
}

extern "C" void kernel_launch(void* const* d_in, const int* in_sizes, int n_in,
                              void* d_out, int out_size, void* d_ws, size_t ws_size,
                              hipStream_t stream) {
  (void)in_sizes; (void)n_in; (void)out_size; (void)ws_size;
  const float* facts    = (const float*)d_in[0];
  const float* question = (const float*)d_in[1];
  const float* W1       = (const float*)d_in[2];
  const float* b1       = (const float*)d_in[3];
  const float* W2       = (const float*)d_in[4];
  const float* b2       = (const float*)d_in[5];
  const float* gru_k    = (const float*)d_in[6];
  const float* gru_rk   = (const float*)d_in[7];
  const float* gru_b    = (const float*)d_in[8];
  const float* Wm       = (const float*)d_in[9];
  const float* bm       = (const float*)d_in[10];
  bf16_t* ws = (bf16_t*)d_ws;
  float* fws = (float*)(ws + E_END);
  float* scores_ws = fws + F_SCORES;
  float* mem_ws    = fws + F_MEM;
  float* pfix_ws   = fws + F_PFIX;
  float* out = (float*)d_out;

  prep_weights<<<2048, 256, 0, stream>>>(gru_k, gru_rk, W1, Wm, ws);
  xproj_kernel<<<dim3(128, 8), 512, 0, stream>>>(facts, question, gru_b, ws, mem_ws);
  // ep0: mem==question, scores come out of the fixed kernel directly
  scores_fixed_kernel<<<dim3(128, 8), 256, 0, stream>>>(question, b1, W2, b2, ws, pfix_ws, scores_ws);
  // scans: ep0/ep1 fuse next-episode scores in their epilogue; ep2 writes out
  scan_kernel<<<128, 512, 0, stream>>>(question, bm, W2, b2, ws, scores_ws, mem_ws, pfix_ws, out, 0);
  scan_kernel<<<128, 512, 0, stream>>>(question, bm, W2, b2, ws, scores_ws, mem_ws, pfix_ws, out, 0);
  scan_kernel<<<128, 512, 0, stream>>>(question, bm, W2, b2, ws, scores_ws, mem_ws, pfix_ws, out, 1);
}

// Round 7
// 403.137 us; speedup vs baseline: 1.7117x; 1.1160x over previous
//
#include <hip/hip_runtime.h>
#include <cstdint>
#include <cstddef>

// ---------------------------------------------------------------------------
// Episodic memory module (DMN) on MI355X — round 14.
//
// R13 post-mortem: correctness fail (absmax 1.29) — rkh LDS staging loop
// rewritten for 1024 threads kept trip count 4: staged 4096 bf16x8 units =
// 64KB of the 128KB rkh_lds; S3's kt>=4 half read garbage.  Fix: 8 iters.
// The 16-wave scan restructure itself is unchanged (this round is a clean
// re-test of the 2x-TLP theory).
//
// R13 design recap: 1024-thread scan (16 waves = 4/SIMD).  Wave w: wg=w&7
// (cols [32wg,32wg+32)), mt=w>>3 (M-tile).  S1 duplicated across the mt
// pair; S2/S3/blend split by mt (per-wave S3 32->16 MFMAs); mt=1 blend
// partial crosses via h1part LDS; 3 barriers/chunk.  VGPR cap 128 (16-wave
// WG).  Tripwire: scan WRITE_SIZE ~0.3MB else spill -> revert scan to R10.
// ---------------------------------------------------------------------------

typedef __bf16 bf16_t;
typedef __attribute__((ext_vector_type(8))) __bf16 bf16x8;
typedef __attribute__((ext_vector_type(4))) __bf16 bf16x4;
typedef __attribute__((ext_vector_type(4))) float f32x4;

static __device__ __forceinline__ f32x4 mfma16(bf16x8 a, bf16x8 b, f32x4 c) {
  return __builtin_amdgcn_mfma_f32_16x16x32_bf16(a, b, c, 0, 0, 0);
}
static __device__ __forceinline__ float fast_rcp(float x) { return __builtin_amdgcn_rcpf(x); }
static __device__ __forceinline__ float sigmoid_f(float x) {
  return fast_rcp(1.f + exp2f(-1.44269504f * x));
}
static __device__ __forceinline__ float tanh_f(float x) {
  float e = exp2f(2.88539008f * x);
  return 1.f - 2.f * fast_rcp(e + 1.f);
}
static __device__ __forceinline__ unsigned short f2bf(float x) {
  __bf16 h = (__bf16)x;
  return __builtin_bit_cast(unsigned short, h);
}
// Workgroup barrier WITHOUT the vmcnt(0) drain __syncthreads() carries.
// All call sites are in wave-uniform control flow.
static __device__ __forceinline__ void ldsbar() {
  asm volatile("s_waitcnt lgkmcnt(0)\n\ts_barrier" ::: "memory");
}

// ws layout (bf16 element offsets).  B-fragment layout for a K x N matrix:
// elem(k,n) at ((kt*NT + nt)*64 + lane)*8 + j, kt=k/32, nt=n/16,
// lane=((k%32)/8)*16 + (n%16), j=k%8.
static constexpr size_t E_GRUK  = 0;                            // K=256 N=512
static constexpr size_t E_RKR   = 131072;                       // K=256 N=256
static constexpr size_t E_RKH   = 196608;
static constexpr size_t E_W1F   = 262144;                       // K=1024 N=64
static constexpr size_t E_WMF   = 327680;                       // K=768 N=256
static constexpr size_t E_XR    = 524288;                       // + b*131072 (A-frag)
static constexpr size_t E_XHC   = E_XR  + (size_t)128 * 131072; // + b*131072 (C order)
static constexpr size_t E_FACTS = E_XHC + (size_t)128 * 131072; // + b*131072 (A-frag)
static constexpr size_t E_END   = E_FACTS + (size_t)128 * 131072;
static constexpr size_t F_SCORES = 0;
static constexpr size_t F_MEM    = 65536;
static constexpr size_t F_PFIX   = 131072;   // 128*32*4*64 f32x4 = 4M floats

__global__ void prep_weights(const float* __restrict__ gru_k,
                             const float* __restrict__ gru_rk,
                             const float* __restrict__ W1,
                             const float* __restrict__ Wm,
                             bf16_t* __restrict__ ws) {
  size_t idx = (size_t)blockIdx.x * 256 + threadIdx.x;
  if (idx >= 524288) return;
  size_t local; int NT, which;
  if (idx < 131072)      { local = idx;          NT = 32; which = 0; }
  else if (idx < 196608) { local = idx - 131072; NT = 16; which = 1; }
  else if (idx < 262144) { local = idx - 196608; NT = 16; which = 2; }
  else if (idx < 327680) { local = idx - 262144; NT = 4;  which = 3; }
  else                   { local = idx - 327680; NT = 16; which = 4; }
  int j    = (int)(local & 7);
  int lane = (int)((local >> 3) & 63);
  size_t rem = local >> 9;
  int nt = (int)(rem % NT);
  int kt = (int)(rem / NT);
  int k = kt * 32 + (lane >> 4) * 8 + j;
  int n = nt * 16 + (lane & 15);
  float v;
  switch (which) {
    case 0:  v = gru_k[(size_t)k * 768 + 256 + n]; break;
    case 1:  v = gru_rk[(size_t)k * 768 + 256 + n]; break;
    case 2:  v = gru_rk[(size_t)k * 768 + 512 + n]; break;
    case 3:  v = (n < 50) ? W1[(size_t)k * 50 + n] : 0.f; break;
    default: v = Wm[(size_t)k * 256 + n]; break;
  }
  ws[idx] = (__bf16)v;
}

// ------------------------------- kernel A ----------------------------------
// x_proj = facts[b] @ gru_k[:,U:3U] + bias; also persists facts bf16 A-frags.
// grid (b=128, s=8), 512 threads (8 waves, nt=4/wave).  WG does Mt in
// [4s,4s+4) as 2 pair-iterations; each gk fragment feeds 2 A-tiles.
// (512,4): R8-proven config — VGPR 64, no spills, 66us.  (512,8) spilled.
__global__ __launch_bounds__(512, 4)
void xproj_kernel(const float* __restrict__ facts,
                  const float* __restrict__ question,
                  const float* __restrict__ gru_bg,
                  bf16_t* __restrict__ ws,
                  float* __restrict__ mem_ws) {
  const int b = blockIdx.x, s = blockIdx.y;
  const int tid = threadIdx.x, w = tid >> 6, lane = tid & 63;
  const int quad = lane >> 4, col = lane & 15;
  __shared__ float grub[512];
  __shared__ bf16_t fragbuf[8192];   // 2 tiles; logical unit u at u^kt (swizzled)
  __shared__ bf16_t xrtrans[8192];   // 2 tiles; logical unit u at u^((u>>4)&3)
  grub[tid] = gru_bg[256 + tid];     // [0,256)=xr bias, [256,512)=xh bias
  if (s == 0 && tid < 256) mem_ws[b * 256 + tid] = question[(size_t)b * 256 + tid];
  __syncthreads();

  bf16_t* xr_ws = ws + E_XR   + (size_t)b * 131072;
  bf16_t* xh_ws = ws + E_XHC  + (size_t)b * 131072;
  bf16_t* ff_ws = ws + E_FACTS + (size_t)b * 131072;
  const bf16_t* gbase = ws + E_GRUK;
  // staging ownership: 512 threads cover 2 tiles x 16 rows x 16 col-segs
  const int tile = tid >> 8, row = (tid >> 4) & 15, cseg = tid & 15;

  // this thread's two swizzled fragbuf deposit units (constant across iters)
  int wunit[2];
  #pragma unroll
  for (int half = 0; half < 2; ++half) {
    int u0 = cseg * 16 + half * 8;
    int kt = u0 >> 5, qk = (u0 >> 3) & 3;
    int u = kt * 64 + qk * 16 + row;
    wunit[half] = tile * 512 + (u ^ kt);
  }

  for (int it = 0; it < 2; ++it) {
    const int Mt0 = s * 4 + 2 * it;
    // stage this thread's 16 facts floats (one tile each; 512 thr = 2 tiles)
    float v[16];
    {
      const float* src = facts + (((size_t)b * 512) + (Mt0 + tile) * 16 + row) * 256 + cseg * 16;
      #pragma unroll
      for (int i = 0; i < 4; ++i) {
        f32x4 t4 = ((const f32x4*)src)[i];
        v[4*i] = t4[0]; v[4*i+1] = t4[1]; v[4*i+2] = t4[2]; v[4*i+3] = t4[3];
      }
    }
    #pragma unroll
    for (int half = 0; half < 2; ++half) {
      bf16x8 pk;
      #pragma unroll
      for (int j = 0; j < 8; ++j) pk[j] = (__bf16)v[half * 8 + j];
      *(bf16x8*)&fragbuf[wunit[half] * 8] = pk;
    }
    ldsbar();  // bar1: fragbuf visible
    { // persist facts frags for scores (unswizzle -> ws holds logical layout)
      #pragma unroll
      for (int e = 0; e < 2; ++e) {
        int p = 2 * tid + e;
        int t = p >> 9, pu = p & 511;
        int qu = pu ^ (pu >> 6);
        bf16x8 f = *(bf16x8*)&fragbuf[(t * 512 + qu) * 8];
        *(bf16x8*)(ff_ws + (size_t)(Mt0 + t) * 4096 + (size_t)pu * 8) = f;
      }
    }
    // paired MFMA: each gk fragment load feeds BOTH A-tiles; wave owns nt=4
    f32x4 acc[2][4];
    #pragma unroll
    for (int t = 0; t < 2; ++t)
      #pragma unroll
      for (int nt = 0; nt < 4; ++nt) acc[t][nt] = (f32x4){0.f, 0.f, 0.f, 0.f};
    #pragma unroll
    for (int kt = 0; kt < 8; ++kt) {
      int us = (kt * 64 + lane) ^ kt;
      bf16x8 af0 = *(const bf16x8*)&fragbuf[(size_t)us * 8];
      bf16x8 af1 = *(const bf16x8*)&fragbuf[(size_t)(512 + us) * 8];
      #pragma unroll
      for (int nt = 0; nt < 4; ++nt) {
        bf16x8 g = *(const bf16x8*)(gbase + (((size_t)kt * 32 + (w * 4 + nt)) * 64 + lane) * 8);
        acc[0][nt] = mfma16(af0, g, acc[0][nt]);
        acc[1][nt] = mfma16(af1, g, acc[1][nt]);
      }
    }
    // epilogue: waves 0-3 -> xr (transpose via swizzled LDS), 4-7 -> xh
    #pragma unroll
    for (int t = 0; t < 2; ++t)
      #pragma unroll
      for (int nt = 0; nt < 4; ++nt) {
        int o = w * 64 + nt * 16 + col;
        float bias = grub[o];
        if (o < 256) { // wave-uniform: w < 4
          int ktA = o >> 5, qkA = (o >> 3) & 3, j = o & 7;
          #pragma unroll
          for (int r = 0; r < 4; ++r) {
            int u = ktA * 64 + qkA * 16 + (quad * 4 + r);
            int us2 = u ^ ((u >> 4) & 3);
            xrtrans[(t * 512 + us2) * 8 + j] = (__bf16)(acc[t][nt][r] + bias);
          }
        } else {       // wave-uniform: w >= 4
          int ntx = (o >> 4) - 16;
          unsigned short s0 = f2bf(acc[t][nt][0] + bias), s1 = f2bf(acc[t][nt][1] + bias);
          unsigned short s2 = f2bf(acc[t][nt][2] + bias), s3 = f2bf(acc[t][nt][3] + bias);
          uint2 pv;
          pv.x = (unsigned)s0 | ((unsigned)s1 << 16);
          pv.y = (unsigned)s2 | ((unsigned)s3 << 16);
          *(uint2*)(xh_ws + ((size_t)(Mt0 + t) * 16 + ntx) * 256 + lane * 4) = pv;
        }
      }
    ldsbar();  // bar2: xrtrans visible
    { // xr store: read swizzled, write logical (ws layout unchanged for scan)
      #pragma unroll
      for (int e = 0; e < 2; ++e) {
        int p = 2 * tid + e;
        int t = p >> 9, pu = p & 511;
        int qu = pu ^ ((pu >> 4) & 3);
        bf16x8 f = *(bf16x8*)&xrtrans[(t * 512 + qu) * 8];
        *(bf16x8*)(xr_ws + (size_t)(Mt0 + t) * 4096 + (size_t)pu * 8) = f;
      }
    }
    // no bar3: next iteration's bar1 orders xrtrans reads vs next writes.
  }
}

// ---------------------------- kernel B0 (once) -----------------------------
// P_fixed = (f.q)@W1[0:256] + |f-q|@W1[512:768] + b1 for all (b, n, h),
// AND episode-0 scores (mem==question at ep0 so m-frags == q-frags).
// pfix stored in C-frag order (f32x4/lane) as the later-episode acc init.
__global__ __launch_bounds__(256)
void scores_fixed_kernel(const float* __restrict__ question,
                         const float* __restrict__ b1g,
                         const float* __restrict__ W2g,
                         const float* __restrict__ b2g,
                         const bf16_t* __restrict__ ws,
                         float* __restrict__ pfix,
                         float* __restrict__ scores_ws) {
  const int b = blockIdx.x, s = blockIdx.y;
  const int tid = threadIdx.x, w = tid >> 6, lane = tid & 63;
  const int quad = lane >> 4, col = lane & 15;
  __shared__ float q_lds[256], b1_lds[64], W2_lds[64], score_lds[64];
  __shared__ float b2s;
  q_lds[tid] = question[(size_t)b * 256 + tid];
  if (tid < 64) {
    b1_lds[tid] = (tid < 50) ? b1g[tid] : 0.f;
    W2_lds[tid] = (tid < 50) ? W2g[tid] : 0.f;
  }
  if (tid == 0) b2s = b2g[0];
  __syncthreads();
  if (tid < 64) score_lds[tid] = b2s;
  __syncthreads();

  const bf16_t* ffb = ws + E_FACTS + (size_t)b * 131072 + (size_t)s * 4 * 4096;
  const bf16_t* w1b = ws + E_W1F;

  f32x4 accq[4], accm[4];
  #pragma unroll
  for (int mt = 0; mt < 4; ++mt) {
    accq[mt] = (f32x4){0.f, 0.f, 0.f, 0.f};
    accm[mt] = (f32x4){0.f, 0.f, 0.f, 0.f};
  }

  #pragma unroll 2
  for (int kt = 0; kt < 8; ++kt) {
    bf16x8 wf0 = *(const bf16x8*)(w1b + (((size_t)(kt)      * 4 + w) * 64 + lane) * 8);
    bf16x8 wf1 = *(const bf16x8*)(w1b + (((size_t)(8  + kt) * 4 + w) * 64 + lane) * 8);
    bf16x8 wf2 = *(const bf16x8*)(w1b + (((size_t)(16 + kt) * 4 + w) * 64 + lane) * 8);
    bf16x8 wf3 = *(const bf16x8*)(w1b + (((size_t)(24 + kt) * 4 + w) * 64 + lane) * 8);
    const f32x4* qp = (const f32x4*)&q_lds[kt * 32 + quad * 8];
    f32x4 qa = qp[0], qb = qp[1];
    float qv[8] = {qa[0],qa[1],qa[2],qa[3],qb[0],qb[1],qb[2],qb[3]};
    #pragma unroll
    for (int mt = 0; mt < 4; ++mt) {
      bf16x8 f8 = *(const bf16x8*)(ffb + (size_t)mt * 4096 + (kt * 64 + lane) * 8);
      bf16x8 a0, a2;
      #pragma unroll
      for (int j = 0; j < 8; ++j) {
        float fu = (float)f8[j];
        a0[j] = (__bf16)(fu * qv[j]);
        a2[j] = (__bf16)fabsf(fu - qv[j]);
      }
      accq[mt] = mfma16(a0, wf0, accq[mt]);
      accq[mt] = mfma16(a2, wf2, accq[mt]);
      accm[mt] = mfma16(a0, wf1, accm[mt]);
      accm[mt] = mfma16(a2, wf3, accm[mt]);
    }
  }
  int hcol = w * 16 + col;
  float pb1 = b1_lds[hcol], pw2 = W2_lds[hcol];
  f32x4* po = (f32x4*)pfix;
  #pragma unroll
  for (int mt = 0; mt < 4; ++mt) {
    // pfix = q-terms + b1 (the later-episode accumulator seed)
    f32x4 o = accq[mt];
    #pragma unroll
    for (int r = 0; r < 4; ++r) o[r] += pb1;
    po[(((size_t)b * 32 + s * 4 + mt) * 4 + w) * 64 + lane] = o;
    // ep0 score partial: tanh(pfix + m-terms) * W2  (mem==q at ep0)
    float p[4];
    #pragma unroll
    for (int r = 0; r < 4; ++r) p[r] = tanh_f(o[r] + accm[mt][r]) * pw2;
    #pragma unroll
    for (int r = 0; r < 4; ++r) {
      p[r] += __shfl_xor(p[r], 1, 64);
      p[r] += __shfl_xor(p[r], 2, 64);
      p[r] += __shfl_xor(p[r], 4, 64);
      p[r] += __shfl_xor(p[r], 8, 64);
    }
    if (col == 0) {
      #pragma unroll
      for (int r = 0; r < 4; ++r)
        atomicAdd(&score_lds[mt * 16 + quad * 4 + r], p[r]);
    }
  }
  __syncthreads();
  if (tid < 64) scores_ws[(size_t)b * 512 + s * 64 + tid] = score_lds[tid];
}

// ------------------------------- kernel B ----------------------------------
// scores[b, n] for episodes 1,2: m-terms only on top of P_fixed.
// grid (b=128, s=8); WG does rows [64s,64s+64).  (R10-proven, ~34us)
__global__ __launch_bounds__(256)
void scores_kernel(const float* __restrict__ W2g,
                   const float* __restrict__ b2g,
                   const bf16_t* __restrict__ ws,
                   const float* __restrict__ mem_ws,
                   const float* __restrict__ pfix,
                   float* __restrict__ scores_ws) {
  const int b = blockIdx.x, s = blockIdx.y;
  const int tid = threadIdx.x, w = tid >> 6, lane = tid & 63;
  const int quad = lane >> 4, col = lane & 15;
  __shared__ float mem_lds[256], W2_lds[64], score_lds[64];
  __shared__ float b2s;
  mem_lds[tid] = mem_ws[(size_t)b * 256 + tid];
  if (tid < 64) W2_lds[tid] = (tid < 50) ? W2g[tid] : 0.f;
  if (tid == 0) b2s = b2g[0];
  __syncthreads();
  if (tid < 64) score_lds[tid] = b2s;
  __syncthreads();

  const bf16_t* ffb = ws + E_FACTS + (size_t)b * 131072 + (size_t)s * 4 * 4096;
  const bf16_t* w1b = ws + E_W1F;
  const f32x4* pf = (const f32x4*)pfix;

  f32x4 acc[4];
  #pragma unroll
  for (int mt = 0; mt < 4; ++mt)
    acc[mt] = pf[(((size_t)b * 32 + s * 4 + mt) * 4 + w) * 64 + lane];

  #pragma unroll 2
  for (int kt = 0; kt < 8; ++kt) {
    bf16x8 wf1 = *(const bf16x8*)(w1b + (((size_t)(8  + kt) * 4 + w) * 64 + lane) * 8);
    bf16x8 wf3 = *(const bf16x8*)(w1b + (((size_t)(24 + kt) * 4 + w) * 64 + lane) * 8);
    const f32x4* mp = (const f32x4*)&mem_lds[kt * 32 + quad * 8];
    f32x4 ma = mp[0], mb = mp[1];
    float mv[8] = {ma[0],ma[1],ma[2],ma[3],mb[0],mb[1],mb[2],mb[3]};
    #pragma unroll
    for (int mt = 0; mt < 4; ++mt) {
      bf16x8 f8 = *(const bf16x8*)(ffb + (size_t)mt * 4096 + (kt * 64 + lane) * 8);
      bf16x8 a1, a3;
      #pragma unroll
      for (int j = 0; j < 8; ++j) {
        float fu = (float)f8[j];
        a1[j] = (__bf16)(fu * mv[j]);
        a3[j] = (__bf16)fabsf(fu - mv[j]);
      }
      acc[mt] = mfma16(a1, wf1, acc[mt]);
      acc[mt] = mfma16(a3, wf3, acc[mt]);
    }
  }
  int hcol = w * 16 + col;
  float pw2 = W2_lds[hcol];
  #pragma unroll
  for (int mt = 0; mt < 4; ++mt) {
    float p[4];
    #pragma unroll
    for (int r = 0; r < 4; ++r) p[r] = tanh_f(acc[mt][r]) * pw2;
    #pragma unroll
    for (int r = 0; r < 4; ++r) {
      p[r] += __shfl_xor(p[r], 1, 64);
      p[r] += __shfl_xor(p[r], 2, 64);
      p[r] += __shfl_xor(p[r], 4, 64);
      p[r] += __shfl_xor(p[r], 8, 64);
    }
    if (col == 0) {
      #pragma unroll
      for (int r = 0; r < 4; ++r)
        atomicAdd(&score_lds[mt * 16 + quad * 4 + r], p[r]);
    }
  }
  __syncthreads();
  if (tid < 64) scores_ws[(size_t)b * 512 + s * 64 + tid] = score_lds[tid];
}

// ------------------------------- kernel C ----------------------------------
// softmax + chunked-Picard attn-GRU scan (T=32, 16 chunks) + memory update.
// 128 WGs x 1024 threads (16 waves = 4/SIMD).  Wave w: wg=w&7 (cols
// [32wg,32wg+32)), mt=w>>3 (M-tile).  S1 duplicated across the mt pair
// (keeps intra-wave shuffle rv); S2/S3/blend split by mt.  mt=1 blend
// partial -> h1part LDS; 3 barriers/chunk.  h in LDS bf16; fp32 self-term.
__global__ __launch_bounds__(1024, 1)
void scan_kernel(const float* __restrict__ question,
                 const float* __restrict__ bmg,
                 const bf16_t* __restrict__ ws,
                 const float* __restrict__ scores_ws,
                 float* __restrict__ mem_ws,
                 float* __restrict__ out,
                 int last) {
  const int b = blockIdx.x;
  const int tid = threadIdx.x, w = tid >> 6, lane = tid & 63;
  const int quad = lane >> 4, col = lane & 15;
  const int wg = w & 7, mt = w >> 3;

  __shared__ bf16_t hb_lds[512];        // bf16 h ping-pong [0,256) / [256,512)
  __shared__ float aw_lds[512], pt_lds[16];
  __shared__ float q_lds[256], mem_lds[256], bm_lds[256], red[16];
  __shared__ float h1part[256];         // mt=1 blend partials
  __shared__ bf16_t fragbuf[8192];      // rh A-frags, 2 M-tiles x 4096
  __shared__ bf16_t rkh_lds[65536];     // rkh B-frags, 128KB, staged once

  // stage rkh frags global->LDS, stride-1 per lane (conflict-free, coalesced)
  // 8192 bf16x8 units / 1024 threads = 8 iterations (R13 bug: had 4 = half).
  {
    const bf16x8* srcw = (const bf16x8*)(ws + E_RKH);
    bf16x8* dstw = (bf16x8*)rkh_lds;
    #pragma unroll
    for (int i = 0; i < 8; ++i)
      dstw[(size_t)i * 1024 + tid] = srcw[(size_t)i * 1024 + tid];
  }

  if (tid < 256) {
    q_lds[tid]   = question[(size_t)b * 256 + tid];
    mem_lds[tid] = mem_ws[(size_t)b * 256 + tid];
    bm_lds[tid]  = bmg[tid];
  }
  if (tid < 512) hb_lds[tid] = (__bf16)0.f;

  // softmax over 512 scores: waves 0-7 (tid<512) do the work, barriers global
  float s0 = 0.f, e0 = 0.f;
  if (tid < 512) {
    s0 = scores_ws[(size_t)b * 512 + tid];
    float mx = s0;
    #pragma unroll
    for (int o = 32; o > 0; o >>= 1) mx = fmaxf(mx, __shfl_xor(mx, o, 64));
    if (lane == 0) red[w] = mx;
  }
  __syncthreads();
  if (tid < 512) {
    float gmax = red[0];
    #pragma unroll
    for (int i = 1; i < 8; ++i) gmax = fmaxf(gmax, red[i]);
    e0 = __expf(s0 - gmax);
    float sm = e0;
    #pragma unroll
    for (int o = 32; o > 0; o >>= 1) sm += __shfl_xor(sm, o, 64);
    if (lane == 0) red[8 + w] = sm;
  }
  __syncthreads();
  if (tid < 512) {
    float tot = red[8];
    #pragma unroll
    for (int i = 9; i < 16; ++i) tot += red[i];
    aw_lds[tid] = e0 * fast_rcp(tot);
  }
  ldsbar();
  // per-chunk (T=32) blend weights in place:
  // aw[s] := a_s * prod_{j>s in chunk}(1-a_j),  pt[ct] := prod(1-a) over chunk
  if (tid < 16) {
    float av[32];
    #pragma unroll
    for (int j = 0; j < 32; ++j) av[j] = aw_lds[tid * 32 + j];
    float suf = 1.f;
    #pragma unroll
    for (int j = 31; j >= 0; --j) {
      aw_lds[tid * 32 + j] = av[j] * suf;
      suf *= (1.f - av[j]);
    }
    pt_lds[tid] = suf;
  }
  ldsbar();  // also covers rkh_lds staging visibility (lgkmcnt drains ds_writes)

  // S1 recurrence weights: wg owns out cols [32wg, 32wg+32); 64 VGPR.
  // Duplicated across the mt pair (both waves run S1).
  const bf16_t* xrb = ws + E_XR  + (size_t)b * 131072;
  const bf16_t* xhb = ws + E_XHC + (size_t)b * 131072;
  bf16x8 fr[2][8];
  {
    const bf16_t* rb = ws + E_RKR;
    #pragma unroll
    for (int nt = 0; nt < 2; ++nt)
      #pragma unroll
      for (int kt = 0; kt < 8; ++kt) {
        size_t off = (((size_t)kt * 16 + (wg * 2 + nt)) * 64 + lane) * 8;
        fr[nt][kt] = *(const bf16x8*)(rb + off);
      }
  }
  // chunk-0 xr (A-frag, kt=wg, own mt) and xh (C order, 2 nt, own mt)
  bf16x8 xf_c;
  bf16x4 xh_c[2];
  xf_c = *(const bf16x8*)(xrb + (size_t)mt * 4096 + ((size_t)wg * 64 + lane) * 8);
  #pragma unroll
  for (int nt = 0; nt < 2; ++nt)
    xh_c[nt] = *(const bf16x4*)(xhb + ((size_t)mt * 16 + wg * 2 + nt) * 256 + lane * 4);

  bf16_t* hbc = &hb_lds[0];
  bf16_t* hbn = &hb_lds[256];
  float hs0 = 0.f, hs1 = 0.f;  // fp32 self-copy (mt=0 waves authoritative)

  for (int ct = 0; ct < 16; ++ct) {
    // S1: rv0 = h @ rkr (both mt waves duplicate).  Split-K 2 chains of 4.
    f32x4 z = (f32x4){0.f,0.f,0.f,0.f};
    f32x4 a0a = z, a0b = z, a1a = z, a1b = z;
    #pragma unroll
    for (int kt = 0; kt < 4; ++kt) {
      bf16x8 hf = *(const bf16x8*)&hbc[kt * 32 + quad * 8];
      a0a = mfma16(hf, fr[0][kt], a0a);
      a1a = mfma16(hf, fr[1][kt], a1a);
    }
    #pragma unroll
    for (int kt = 4; kt < 8; ++kt) {
      bf16x8 hf = *(const bf16x8*)&hbc[kt * 32 + quad * 8];
      a0b = mfma16(hf, fr[0][kt], a0b);
      a1b = mfma16(hf, fr[1][kt], a1b);
    }
    f32x4 ac0 = a0a + a0b, ac1 = a1a + a1b;
    // rv via intra-wave shuffles (producing wave == consuming wave):
    float rv[8];
    #pragma unroll
    for (int j = 0; j < 8; ++j) {
      int c = quad * 8 + j;
      float v0 = __shfl(ac0[0], c & 15, 64);
      float v1 = __shfl(ac1[0], c & 15, 64);
      rv[j] = (c < 16) ? v0 : v1;
    }
    // S2: rh A-frag (kt=wg) for OWN M-tile only
    {
      bf16x8 aW = *(const bf16x8*)&hbc[wg * 32 + quad * 8];
      bf16x8 rh;
      #pragma unroll
      for (int j = 0; j < 8; ++j)
        rh[j] = (__bf16)(sigmoid_f((float)xf_c[j] + rv[j]) * (float)aW[j]);
      *(bf16x8*)&fragbuf[mt * 4096 + (wg * 64 + lane) * 8] = rh;
    }
    ldsbar();  // bar_B: fragbuf visible
    // prefetch next chunk's xr/xh (own mt; consumed next iteration)
    bf16x8 xf_n;
    bf16x4 xh_n[2];
    {
      int ctn = (ct + 1) & 15;
      xf_n = *(const bf16x8*)(xrb + (size_t)(2 * ctn + mt) * 4096 + ((size_t)wg * 64 + lane) * 8);
      #pragma unroll
      for (int nt = 0; nt < 2; ++nt)
        xh_n[nt] = *(const bf16x4*)(xhb + ((size_t)(2 * ctn + mt) * 16 + wg * 2 + nt) * 256 + lane * 4);
    }
    // S3: HH = rh @ rkh for OWN M-tile (2 chains of 8)
    f32x4 aH0 = z, aH1 = z;
    #pragma unroll
    for (int kt = 0; kt < 8; ++kt) {
      bf16x8 f0 = *(const bf16x8*)&rkh_lds[(((size_t)kt * 16 + wg * 2)     * 64 + lane) * 8];
      bf16x8 f1 = *(const bf16x8*)&rkh_lds[(((size_t)kt * 16 + wg * 2 + 1) * 64 + lane) * 8];
      bf16x8 a = *(const bf16x8*)&fragbuf[mt * 4096 + (kt * 64 + lane) * 8];
      aH0 = mfma16(a, f0, aH0);
      aH1 = mfma16(a, f1, aH1);
    }
    // blend own mt: partial = sum_{s in own half} aw[s]*tanh(xh+HH)[s]
    const float* awp = &aw_lds[ct * 32];
    f32x4 wq = *(const f32x4*)&awp[mt * 16 + quad * 4];
    float Pt = pt_lds[ct];
    float part0 = 0.f, part1 = 0.f;
    #pragma unroll
    for (int r = 0; r < 4; ++r) {
      part0 += wq[r] * tanh_f((float)xh_c[0][r] + aH0[r]);
      part1 += wq[r] * tanh_f((float)xh_c[1][r] + aH1[r]);
    }
    part0 += __shfl_xor(part0, 16, 64); part0 += __shfl_xor(part0, 32, 64);
    part1 += __shfl_xor(part1, 16, 64); part1 += __shfl_xor(part1, 32, 64);
    if (mt == 1) {           // wave-uniform branch
      if (quad == 0) {
        h1part[wg * 32 + col]      = part0;
        h1part[wg * 32 + 16 + col] = part1;
      }
    }
    ldsbar();  // bar_C: h1part visible
    if (mt == 0) {           // wave-uniform branch
      float hn0 = Pt * hs0 + part0 + h1part[wg * 32 + col];
      float hn1 = Pt * hs1 + part1 + h1part[wg * 32 + 16 + col];
      hs0 = hn0; hs1 = hn1;
      if (quad == 0) {
        hbn[wg * 32 + col]      = (__bf16)hn0;
        hbn[wg * 32 + 16 + col] = (__bf16)hn1;
      }
    }
    ldsbar();  // bar_D: new h visible; fragbuf free
    { bf16_t* t = hbc; hbc = hbn; hbn = t; }
    xf_c = xf_n;
    xh_c[0] = xh_n[0];
    xh_c[1] = xh_n[1];
  }
  // hbc now holds the episode vector (bf16)

  // phase D: memory = relu([mem, episode, q] @ Wm + bm); wave w -> nt=w
  {
    f32x4 am_a = (f32x4){0.f,0.f,0.f,0.f}, am_b = am_a;
    const bf16_t* wmb = ws + E_WMF;
    #pragma unroll
    for (int kt = 0; kt < 24; ++kt) {
      bf16x8 a;
      if (kt >= 8 && kt < 16) {           // episode: already bf16, broadcast read
        a = *(const bf16x8*)&hbc[(kt - 8) * 32 + quad * 8];
      } else {
        const float* sv = (kt < 8) ? &mem_lds[kt * 32] : &q_lds[(kt - 16) * 32];
        const f32x4* vp = (const f32x4*)&sv[quad * 8];
        f32x4 va = vp[0], vb = vp[1];
        #pragma unroll
        for (int j = 0; j < 4; ++j) { a[j] = (__bf16)va[j]; a[4 + j] = (__bf16)vb[j]; }
      }
      bf16x8 bf = *(const bf16x8*)(wmb + (((size_t)kt * 16 + w) * 64 + lane) * 8);
      if (kt & 1) am_b = mfma16(a, bf, am_b);
      else        am_a = mfma16(a, bf, am_a);
    }
    if (quad == 0) {
      int v = w * 16 + col;
      float r = fmaxf(am_a[0] + am_b[0] + bm_lds[v], 0.f);
      mem_ws[(size_t)b * 256 + v] = r;
      if (last) out[(size_t)b * 256 + v] = r;
    }
  }
}

extern "C" void kernel_launch(void* const* d_in, const int* in_sizes, int n_in,
                              void* d_out, int out_size, void* d_ws, size_t ws_size,
                              hipStream_t stream) {
  (void)in_sizes; (void)n_in; (void)out_size; (void)ws_size;
  const float* facts    = (const float*)d_in[0];
  const float* question = (const float*)d_in[1];
  const float* W1       = (const float*)d_in[2];
  const float* b1       = (const float*)d_in[3];
  const float* W2       = (const float*)d_in[4];
  const float* b2       = (const float*)d_in[5];
  const float* gru_k    = (const float*)d_in[6];
  const float* gru_rk   = (const float*)d_in[7];
  const float* gru_b    = (const float*)d_in[8];
  const float* Wm       = (const float*)d_in[9];
  const float* bm       = (const float*)d_in[10];
  bf16_t* ws = (bf16_t*)d_ws;
  float* fws = (float*)(ws + E_END);
  float* scores_ws = fws + F_SCORES;
  float* mem_ws    = fws + F_MEM;
  float* pfix_ws   = fws + F_PFIX;
  float* out = (float*)d_out;

  prep_weights<<<2048, 256, 0, stream>>>(gru_k, gru_rk, W1, Wm, ws);
  xproj_kernel<<<dim3(128, 8), 512, 0, stream>>>(facts, question, gru_b, ws, mem_ws);
  // ep0: mem==question, scores come out of the fixed kernel directly
  scores_fixed_kernel<<<dim3(128, 8), 256, 0, stream>>>(question, b1, W2, b2, ws, pfix_ws, scores_ws);
  for (int ep = 0; ep < 3; ++ep) {
    scan_kernel<<<128, 1024, 0, stream>>>(question, bm, ws, scores_ws, mem_ws, out, ep == 2);
    if (ep < 2)
      scores_kernel<<<dim3(128, 8), 256, 0, stream>>>(W2, b2, ws, mem_ws, pfix_ws, scores_ws);
  }
}

// Round 8
// 401.450 us; speedup vs baseline: 1.7188x; 1.0042x over previous
//
#include <hip/hip_runtime.h>
#include <cstdint>
#include <cstddef>

// ---------------------------------------------------------------------------
// Episodic memory module (DMN) on MI355X — round 15.
//
// R14 post-mortem: 2x-TLP theory refuted — Occ doubled (20%) but scan dur
// 62->66us.  Smoking gun: VGPR_Count=64 < fr's 64 VGPRs => compiler streams
// rkr fragments from L2 EVERY chunk.  16 waves x 16 frags x 64B x 16 chunks
// x 128 WGs = 33.5MB == the 38.7MB FETCH.  These loads sit right after the
// h barrier with zero prefetch cover -> the per-chunk latency floor.  The
// compiler chose 64 VGPR to enable 2 WGs/CU, but grid=128 on 256 CUs means
// a 2nd WG can never exist.
//
// R15 (one line): scan __launch_bounds__(1024, 4) — declares 1 WG/CU
// (4 waves/EU), raising the VGPR budget to 128 so fr stays register-
// resident.  Pure relaxation: cannot spill, cannot cost occupancy.
// Tripwire: VGPR must rise to ~115-128 and FETCH drop to ~6MB; else the
// heuristic ignored the hint -> plan B = rkr in LDS, rkh streamed+prefetched.
// ---------------------------------------------------------------------------

typedef __bf16 bf16_t;
typedef __attribute__((ext_vector_type(8))) __bf16 bf16x8;
typedef __attribute__((ext_vector_type(4))) __bf16 bf16x4;
typedef __attribute__((ext_vector_type(4))) float f32x4;

static __device__ __forceinline__ f32x4 mfma16(bf16x8 a, bf16x8 b, f32x4 c) {
  return __builtin_amdgcn_mfma_f32_16x16x32_bf16(a, b, c, 0, 0, 0);
}
static __device__ __forceinline__ float fast_rcp(float x) { return __builtin_amdgcn_rcpf(x); }
static __device__ __forceinline__ float sigmoid_f(float x) {
  return fast_rcp(1.f + exp2f(-1.44269504f * x));
}
static __device__ __forceinline__ float tanh_f(float x) {
  float e = exp2f(2.88539008f * x);
  return 1.f - 2.f * fast_rcp(e + 1.f);
}
static __device__ __forceinline__ unsigned short f2bf(float x) {
  __bf16 h = (__bf16)x;
  return __builtin_bit_cast(unsigned short, h);
}
// Workgroup barrier WITHOUT the vmcnt(0) drain __syncthreads() carries.
// All call sites are in wave-uniform control flow.
static __device__ __forceinline__ void ldsbar() {
  asm volatile("s_waitcnt lgkmcnt(0)\n\ts_barrier" ::: "memory");
}

// ws layout (bf16 element offsets).  B-fragment layout for a K x N matrix:
// elem(k,n) at ((kt*NT + nt)*64 + lane)*8 + j, kt=k/32, nt=n/16,
// lane=((k%32)/8)*16 + (n%16), j=k%8.
static constexpr size_t E_GRUK  = 0;                            // K=256 N=512
static constexpr size_t E_RKR   = 131072;                       // K=256 N=256
static constexpr size_t E_RKH   = 196608;
static constexpr size_t E_W1F   = 262144;                       // K=1024 N=64
static constexpr size_t E_WMF   = 327680;                       // K=768 N=256
static constexpr size_t E_XR    = 524288;                       // + b*131072 (A-frag)
static constexpr size_t E_XHC   = E_XR  + (size_t)128 * 131072; // + b*131072 (C order)
static constexpr size_t E_FACTS = E_XHC + (size_t)128 * 131072; // + b*131072 (A-frag)
static constexpr size_t E_END   = E_FACTS + (size_t)128 * 131072;
static constexpr size_t F_SCORES = 0;
static constexpr size_t F_MEM    = 65536;
static constexpr size_t F_PFIX   = 131072;   // 128*32*4*64 f32x4 = 4M floats

__global__ void prep_weights(const float* __restrict__ gru_k,
                             const float* __restrict__ gru_rk,
                             const float* __restrict__ W1,
                             const float* __restrict__ Wm,
                             bf16_t* __restrict__ ws) {
  size_t idx = (size_t)blockIdx.x * 256 + threadIdx.x;
  if (idx >= 524288) return;
  size_t local; int NT, which;
  if (idx < 131072)      { local = idx;          NT = 32; which = 0; }
  else if (idx < 196608) { local = idx - 131072; NT = 16; which = 1; }
  else if (idx < 262144) { local = idx - 196608; NT = 16; which = 2; }
  else if (idx < 327680) { local = idx - 262144; NT = 4;  which = 3; }
  else                   { local = idx - 327680; NT = 16; which = 4; }
  int j    = (int)(local & 7);
  int lane = (int)((local >> 3) & 63);
  size_t rem = local >> 9;
  int nt = (int)(rem % NT);
  int kt = (int)(rem / NT);
  int k = kt * 32 + (lane >> 4) * 8 + j;
  int n = nt * 16 + (lane & 15);
  float v;
  switch (which) {
    case 0:  v = gru_k[(size_t)k * 768 + 256 + n]; break;
    case 1:  v = gru_rk[(size_t)k * 768 + 256 + n]; break;
    case 2:  v = gru_rk[(size_t)k * 768 + 512 + n]; break;
    case 3:  v = (n < 50) ? W1[(size_t)k * 50 + n] : 0.f; break;
    default: v = Wm[(size_t)k * 256 + n]; break;
  }
  ws[idx] = (__bf16)v;
}

// ------------------------------- kernel A ----------------------------------
// x_proj = facts[b] @ gru_k[:,U:3U] + bias; also persists facts bf16 A-frags.
// grid (b=128, s=8), 512 threads (8 waves, nt=4/wave).  WG does Mt in
// [4s,4s+4) as 2 pair-iterations; each gk fragment feeds 2 A-tiles.
// (512,4): R8-proven config — VGPR 64, no spills, 66us.  (512,8) spilled.
__global__ __launch_bounds__(512, 4)
void xproj_kernel(const float* __restrict__ facts,
                  const float* __restrict__ question,
                  const float* __restrict__ gru_bg,
                  bf16_t* __restrict__ ws,
                  float* __restrict__ mem_ws) {
  const int b = blockIdx.x, s = blockIdx.y;
  const int tid = threadIdx.x, w = tid >> 6, lane = tid & 63;
  const int quad = lane >> 4, col = lane & 15;
  __shared__ float grub[512];
  __shared__ bf16_t fragbuf[8192];   // 2 tiles; logical unit u at u^kt (swizzled)
  __shared__ bf16_t xrtrans[8192];   // 2 tiles; logical unit u at u^((u>>4)&3)
  grub[tid] = gru_bg[256 + tid];     // [0,256)=xr bias, [256,512)=xh bias
  if (s == 0 && tid < 256) mem_ws[b * 256 + tid] = question[(size_t)b * 256 + tid];
  __syncthreads();

  bf16_t* xr_ws = ws + E_XR   + (size_t)b * 131072;
  bf16_t* xh_ws = ws + E_XHC  + (size_t)b * 131072;
  bf16_t* ff_ws = ws + E_FACTS + (size_t)b * 131072;
  const bf16_t* gbase = ws + E_GRUK;
  // staging ownership: 512 threads cover 2 tiles x 16 rows x 16 col-segs
  const int tile = tid >> 8, row = (tid >> 4) & 15, cseg = tid & 15;

  // this thread's two swizzled fragbuf deposit units (constant across iters)
  int wunit[2];
  #pragma unroll
  for (int half = 0; half < 2; ++half) {
    int u0 = cseg * 16 + half * 8;
    int kt = u0 >> 5, qk = (u0 >> 3) & 3;
    int u = kt * 64 + qk * 16 + row;
    wunit[half] = tile * 512 + (u ^ kt);
  }

  for (int it = 0; it < 2; ++it) {
    const int Mt0 = s * 4 + 2 * it;
    // stage this thread's 16 facts floats (one tile each; 512 thr = 2 tiles)
    float v[16];
    {
      const float* src = facts + (((size_t)b * 512) + (Mt0 + tile) * 16 + row) * 256 + cseg * 16;
      #pragma unroll
      for (int i = 0; i < 4; ++i) {
        f32x4 t4 = ((const f32x4*)src)[i];
        v[4*i] = t4[0]; v[4*i+1] = t4[1]; v[4*i+2] = t4[2]; v[4*i+3] = t4[3];
      }
    }
    #pragma unroll
    for (int half = 0; half < 2; ++half) {
      bf16x8 pk;
      #pragma unroll
      for (int j = 0; j < 8; ++j) pk[j] = (__bf16)v[half * 8 + j];
      *(bf16x8*)&fragbuf[wunit[half] * 8] = pk;
    }
    ldsbar();  // bar1: fragbuf visible
    { // persist facts frags for scores (unswizzle -> ws holds logical layout)
      #pragma unroll
      for (int e = 0; e < 2; ++e) {
        int p = 2 * tid + e;
        int t = p >> 9, pu = p & 511;
        int qu = pu ^ (pu >> 6);
        bf16x8 f = *(bf16x8*)&fragbuf[(t * 512 + qu) * 8];
        *(bf16x8*)(ff_ws + (size_t)(Mt0 + t) * 4096 + (size_t)pu * 8) = f;
      }
    }
    // paired MFMA: each gk fragment load feeds BOTH A-tiles; wave owns nt=4
    f32x4 acc[2][4];
    #pragma unroll
    for (int t = 0; t < 2; ++t)
      #pragma unroll
      for (int nt = 0; nt < 4; ++nt) acc[t][nt] = (f32x4){0.f, 0.f, 0.f, 0.f};
    #pragma unroll
    for (int kt = 0; kt < 8; ++kt) {
      int us = (kt * 64 + lane) ^ kt;
      bf16x8 af0 = *(const bf16x8*)&fragbuf[(size_t)us * 8];
      bf16x8 af1 = *(const bf16x8*)&fragbuf[(size_t)(512 + us) * 8];
      #pragma unroll
      for (int nt = 0; nt < 4; ++nt) {
        bf16x8 g = *(const bf16x8*)(gbase + (((size_t)kt * 32 + (w * 4 + nt)) * 64 + lane) * 8);
        acc[0][nt] = mfma16(af0, g, acc[0][nt]);
        acc[1][nt] = mfma16(af1, g, acc[1][nt]);
      }
    }
    // epilogue: waves 0-3 -> xr (transpose via swizzled LDS), 4-7 -> xh
    #pragma unroll
    for (int t = 0; t < 2; ++t)
      #pragma unroll
      for (int nt = 0; nt < 4; ++nt) {
        int o = w * 64 + nt * 16 + col;
        float bias = grub[o];
        if (o < 256) { // wave-uniform: w < 4
          int ktA = o >> 5, qkA = (o >> 3) & 3, j = o & 7;
          #pragma unroll
          for (int r = 0; r < 4; ++r) {
            int u = ktA * 64 + qkA * 16 + (quad * 4 + r);
            int us2 = u ^ ((u >> 4) & 3);
            xrtrans[(t * 512 + us2) * 8 + j] = (__bf16)(acc[t][nt][r] + bias);
          }
        } else {       // wave-uniform: w >= 4
          int ntx = (o >> 4) - 16;
          unsigned short s0 = f2bf(acc[t][nt][0] + bias), s1 = f2bf(acc[t][nt][1] + bias);
          unsigned short s2 = f2bf(acc[t][nt][2] + bias), s3 = f2bf(acc[t][nt][3] + bias);
          uint2 pv;
          pv.x = (unsigned)s0 | ((unsigned)s1 << 16);
          pv.y = (unsigned)s2 | ((unsigned)s3 << 16);
          *(uint2*)(xh_ws + ((size_t)(Mt0 + t) * 16 + ntx) * 256 + lane * 4) = pv;
        }
      }
    ldsbar();  // bar2: xrtrans visible
    { // xr store: read swizzled, write logical (ws layout unchanged for scan)
      #pragma unroll
      for (int e = 0; e < 2; ++e) {
        int p = 2 * tid + e;
        int t = p >> 9, pu = p & 511;
        int qu = pu ^ ((pu >> 4) & 3);
        bf16x8 f = *(bf16x8*)&xrtrans[(t * 512 + qu) * 8];
        *(bf16x8*)(xr_ws + (size_t)(Mt0 + t) * 4096 + (size_t)pu * 8) = f;
      }
    }
    // no bar3: next iteration's bar1 orders xrtrans reads vs next writes.
  }
}

// ---------------------------- kernel B0 (once) -----------------------------
// P_fixed = (f.q)@W1[0:256] + |f-q|@W1[512:768] + b1 for all (b, n, h),
// AND episode-0 scores (mem==question at ep0 so m-frags == q-frags).
// pfix stored in C-frag order (f32x4/lane) as the later-episode acc init.
__global__ __launch_bounds__(256)
void scores_fixed_kernel(const float* __restrict__ question,
                         const float* __restrict__ b1g,
                         const float* __restrict__ W2g,
                         const float* __restrict__ b2g,
                         const bf16_t* __restrict__ ws,
                         float* __restrict__ pfix,
                         float* __restrict__ scores_ws) {
  const int b = blockIdx.x, s = blockIdx.y;
  const int tid = threadIdx.x, w = tid >> 6, lane = tid & 63;
  const int quad = lane >> 4, col = lane & 15;
  __shared__ float q_lds[256], b1_lds[64], W2_lds[64], score_lds[64];
  __shared__ float b2s;
  q_lds[tid] = question[(size_t)b * 256 + tid];
  if (tid < 64) {
    b1_lds[tid] = (tid < 50) ? b1g[tid] : 0.f;
    W2_lds[tid] = (tid < 50) ? W2g[tid] : 0.f;
  }
  if (tid == 0) b2s = b2g[0];
  __syncthreads();
  if (tid < 64) score_lds[tid] = b2s;
  __syncthreads();

  const bf16_t* ffb = ws + E_FACTS + (size_t)b * 131072 + (size_t)s * 4 * 4096;
  const bf16_t* w1b = ws + E_W1F;

  f32x4 accq[4], accm[4];
  #pragma unroll
  for (int mt = 0; mt < 4; ++mt) {
    accq[mt] = (f32x4){0.f, 0.f, 0.f, 0.f};
    accm[mt] = (f32x4){0.f, 0.f, 0.f, 0.f};
  }

  #pragma unroll 2
  for (int kt = 0; kt < 8; ++kt) {
    bf16x8 wf0 = *(const bf16x8*)(w1b + (((size_t)(kt)      * 4 + w) * 64 + lane) * 8);
    bf16x8 wf1 = *(const bf16x8*)(w1b + (((size_t)(8  + kt) * 4 + w) * 64 + lane) * 8);
    bf16x8 wf2 = *(const bf16x8*)(w1b + (((size_t)(16 + kt) * 4 + w) * 64 + lane) * 8);
    bf16x8 wf3 = *(const bf16x8*)(w1b + (((size_t)(24 + kt) * 4 + w) * 64 + lane) * 8);
    const f32x4* qp = (const f32x4*)&q_lds[kt * 32 + quad * 8];
    f32x4 qa = qp[0], qb = qp[1];
    float qv[8] = {qa[0],qa[1],qa[2],qa[3],qb[0],qb[1],qb[2],qb[3]};
    #pragma unroll
    for (int mt = 0; mt < 4; ++mt) {
      bf16x8 f8 = *(const bf16x8*)(ffb + (size_t)mt * 4096 + (kt * 64 + lane) * 8);
      bf16x8 a0, a2;
      #pragma unroll
      for (int j = 0; j < 8; ++j) {
        float fu = (float)f8[j];
        a0[j] = (__bf16)(fu * qv[j]);
        a2[j] = (__bf16)fabsf(fu - qv[j]);
      }
      accq[mt] = mfma16(a0, wf0, accq[mt]);
      accq[mt] = mfma16(a2, wf2, accq[mt]);
      accm[mt] = mfma16(a0, wf1, accm[mt]);
      accm[mt] = mfma16(a2, wf3, accm[mt]);
    }
  }
  int hcol = w * 16 + col;
  float pb1 = b1_lds[hcol], pw2 = W2_lds[hcol];
  f32x4* po = (f32x4*)pfix;
  #pragma unroll
  for (int mt = 0; mt < 4; ++mt) {
    // pfix = q-terms + b1 (the later-episode accumulator seed)
    f32x4 o = accq[mt];
    #pragma unroll
    for (int r = 0; r < 4; ++r) o[r] += pb1;
    po[(((size_t)b * 32 + s * 4 + mt) * 4 + w) * 64 + lane] = o;
    // ep0 score partial: tanh(pfix + m-terms) * W2  (mem==q at ep0)
    float p[4];
    #pragma unroll
    for (int r = 0; r < 4; ++r) p[r] = tanh_f(o[r] + accm[mt][r]) * pw2;
    #pragma unroll
    for (int r = 0; r < 4; ++r) {
      p[r] += __shfl_xor(p[r], 1, 64);
      p[r] += __shfl_xor(p[r], 2, 64);
      p[r] += __shfl_xor(p[r], 4, 64);
      p[r] += __shfl_xor(p[r], 8, 64);
    }
    if (col == 0) {
      #pragma unroll
      for (int r = 0; r < 4; ++r)
        atomicAdd(&score_lds[mt * 16 + quad * 4 + r], p[r]);
    }
  }
  __syncthreads();
  if (tid < 64) scores_ws[(size_t)b * 512 + s * 64 + tid] = score_lds[tid];
}

// ------------------------------- kernel B ----------------------------------
// scores[b, n] for episodes 1,2: m-terms only on top of P_fixed.
// grid (b=128, s=8); WG does rows [64s,64s+64).  (R10-proven, ~34us)
__global__ __launch_bounds__(256)
void scores_kernel(const float* __restrict__ W2g,
                   const float* __restrict__ b2g,
                   const bf16_t* __restrict__ ws,
                   const float* __restrict__ mem_ws,
                   const float* __restrict__ pfix,
                   float* __restrict__ scores_ws) {
  const int b = blockIdx.x, s = blockIdx.y;
  const int tid = threadIdx.x, w = tid >> 6, lane = tid & 63;
  const int quad = lane >> 4, col = lane & 15;
  __shared__ float mem_lds[256], W2_lds[64], score_lds[64];
  __shared__ float b2s;
  mem_lds[tid] = mem_ws[(size_t)b * 256 + tid];
  if (tid < 64) W2_lds[tid] = (tid < 50) ? W2g[tid] : 0.f;
  if (tid == 0) b2s = b2g[0];
  __syncthreads();
  if (tid < 64) score_lds[tid] = b2s;
  __syncthreads();

  const bf16_t* ffb = ws + E_FACTS + (size_t)b * 131072 + (size_t)s * 4 * 4096;
  const bf16_t* w1b = ws + E_W1F;
  const f32x4* pf = (const f32x4*)pfix;

  f32x4 acc[4];
  #pragma unroll
  for (int mt = 0; mt < 4; ++mt)
    acc[mt] = pf[(((size_t)b * 32 + s * 4 + mt) * 4 + w) * 64 + lane];

  #pragma unroll 2
  for (int kt = 0; kt < 8; ++kt) {
    bf16x8 wf1 = *(const bf16x8*)(w1b + (((size_t)(8  + kt) * 4 + w) * 64 + lane) * 8);
    bf16x8 wf3 = *(const bf16x8*)(w1b + (((size_t)(24 + kt) * 4 + w) * 64 + lane) * 8);
    const f32x4* mp = (const f32x4*)&mem_lds[kt * 32 + quad * 8];
    f32x4 ma = mp[0], mb = mp[1];
    float mv[8] = {ma[0],ma[1],ma[2],ma[3],mb[0],mb[1],mb[2],mb[3]};
    #pragma unroll
    for (int mt = 0; mt < 4; ++mt) {
      bf16x8 f8 = *(const bf16x8*)(ffb + (size_t)mt * 4096 + (kt * 64 + lane) * 8);
      bf16x8 a1, a3;
      #pragma unroll
      for (int j = 0; j < 8; ++j) {
        float fu = (float)f8[j];
        a1[j] = (__bf16)(fu * mv[j]);
        a3[j] = (__bf16)fabsf(fu - mv[j]);
      }
      acc[mt] = mfma16(a1, wf1, acc[mt]);
      acc[mt] = mfma16(a3, wf3, acc[mt]);
    }
  }
  int hcol = w * 16 + col;
  float pw2 = W2_lds[hcol];
  #pragma unroll
  for (int mt = 0; mt < 4; ++mt) {
    float p[4];
    #pragma unroll
    for (int r = 0; r < 4; ++r) p[r] = tanh_f(acc[mt][r]) * pw2;
    #pragma unroll
    for (int r = 0; r < 4; ++r) {
      p[r] += __shfl_xor(p[r], 1, 64);
      p[r] += __shfl_xor(p[r], 2, 64);
      p[r] += __shfl_xor(p[r], 4, 64);
      p[r] += __shfl_xor(p[r], 8, 64);
    }
    if (col == 0) {
      #pragma unroll
      for (int r = 0; r < 4; ++r)
        atomicAdd(&score_lds[mt * 16 + quad * 4 + r], p[r]);
    }
  }
  __syncthreads();
  if (tid < 64) scores_ws[(size_t)b * 512 + s * 64 + tid] = score_lds[tid];
}

// ------------------------------- kernel C ----------------------------------
// softmax + chunked-Picard attn-GRU scan (T=32, 16 chunks) + memory update.
// 128 WGs x 1024 threads (16 waves = 4/SIMD).  Wave w: wg=w&7 (cols
// [32wg,32wg+32)), mt=w>>3 (M-tile).  S1 duplicated across the mt pair
// (keeps intra-wave shuffle rv); S2/S3/blend split by mt.  mt=1 blend
// partial -> h1part LDS; 3 barriers/chunk.  h in LDS bf16; fp32 self-term.
// R15: __launch_bounds__(1024, 4) = declare 1 WG/CU -> VGPR budget 128 so
// fr (64 VGPR) stays register-resident instead of streaming from L2/chunk.
__global__ __launch_bounds__(1024, 4)
void scan_kernel(const float* __restrict__ question,
                 const float* __restrict__ bmg,
                 const bf16_t* __restrict__ ws,
                 const float* __restrict__ scores_ws,
                 float* __restrict__ mem_ws,
                 float* __restrict__ out,
                 int last) {
  const int b = blockIdx.x;
  const int tid = threadIdx.x, w = tid >> 6, lane = tid & 63;
  const int quad = lane >> 4, col = lane & 15;
  const int wg = w & 7, mt = w >> 3;

  __shared__ bf16_t hb_lds[512];        // bf16 h ping-pong [0,256) / [256,512)
  __shared__ float aw_lds[512], pt_lds[16];
  __shared__ float q_lds[256], mem_lds[256], bm_lds[256], red[16];
  __shared__ float h1part[256];         // mt=1 blend partials
  __shared__ bf16_t fragbuf[8192];      // rh A-frags, 2 M-tiles x 4096
  __shared__ bf16_t rkh_lds[65536];     // rkh B-frags, 128KB, staged once

  // stage rkh frags global->LDS, stride-1 per lane (conflict-free, coalesced)
  // 8192 bf16x8 units / 1024 threads = 8 iterations.
  {
    const bf16x8* srcw = (const bf16x8*)(ws + E_RKH);
    bf16x8* dstw = (bf16x8*)rkh_lds;
    #pragma unroll
    for (int i = 0; i < 8; ++i)
      dstw[(size_t)i * 1024 + tid] = srcw[(size_t)i * 1024 + tid];
  }

  if (tid < 256) {
    q_lds[tid]   = question[(size_t)b * 256 + tid];
    mem_lds[tid] = mem_ws[(size_t)b * 256 + tid];
    bm_lds[tid]  = bmg[tid];
  }
  if (tid < 512) hb_lds[tid] = (__bf16)0.f;

  // softmax over 512 scores: waves 0-7 (tid<512) do the work, barriers global
  float s0 = 0.f, e0 = 0.f;
  if (tid < 512) {
    s0 = scores_ws[(size_t)b * 512 + tid];
    float mx = s0;
    #pragma unroll
    for (int o = 32; o > 0; o >>= 1) mx = fmaxf(mx, __shfl_xor(mx, o, 64));
    if (lane == 0) red[w] = mx;
  }
  __syncthreads();
  if (tid < 512) {
    float gmax = red[0];
    #pragma unroll
    for (int i = 1; i < 8; ++i) gmax = fmaxf(gmax, red[i]);
    e0 = __expf(s0 - gmax);
    float sm = e0;
    #pragma unroll
    for (int o = 32; o > 0; o >>= 1) sm += __shfl_xor(sm, o, 64);
    if (lane == 0) red[8 + w] = sm;
  }
  __syncthreads();
  if (tid < 512) {
    float tot = red[8];
    #pragma unroll
    for (int i = 9; i < 16; ++i) tot += red[i];
    aw_lds[tid] = e0 * fast_rcp(tot);
  }
  ldsbar();
  // per-chunk (T=32) blend weights in place:
  // aw[s] := a_s * prod_{j>s in chunk}(1-a_j),  pt[ct] := prod(1-a) over chunk
  if (tid < 16) {
    float av[32];
    #pragma unroll
    for (int j = 0; j < 32; ++j) av[j] = aw_lds[tid * 32 + j];
    float suf = 1.f;
    #pragma unroll
    for (int j = 31; j >= 0; --j) {
      aw_lds[tid * 32 + j] = av[j] * suf;
      suf *= (1.f - av[j]);
    }
    pt_lds[tid] = suf;
  }
  ldsbar();  // also covers rkh_lds staging visibility (lgkmcnt drains ds_writes)

  // S1 recurrence weights: wg owns out cols [32wg, 32wg+32); 64 VGPR.
  // Duplicated across the mt pair (both waves run S1).
  const bf16_t* xrb = ws + E_XR  + (size_t)b * 131072;
  const bf16_t* xhb = ws + E_XHC + (size_t)b * 131072;
  bf16x8 fr[2][8];
  {
    const bf16_t* rb = ws + E_RKR;
    #pragma unroll
    for (int nt = 0; nt < 2; ++nt)
      #pragma unroll
      for (int kt = 0; kt < 8; ++kt) {
        size_t off = (((size_t)kt * 16 + (wg * 2 + nt)) * 64 + lane) * 8;
        fr[nt][kt] = *(const bf16x8*)(rb + off);
      }
  }
  // chunk-0 xr (A-frag, kt=wg, own mt) and xh (C order, 2 nt, own mt)
  bf16x8 xf_c;
  bf16x4 xh_c[2];
  xf_c = *(const bf16x8*)(xrb + (size_t)mt * 4096 + ((size_t)wg * 64 + lane) * 8);
  #pragma unroll
  for (int nt = 0; nt < 2; ++nt)
    xh_c[nt] = *(const bf16x4*)(xhb + ((size_t)mt * 16 + wg * 2 + nt) * 256 + lane * 4);

  bf16_t* hbc = &hb_lds[0];
  bf16_t* hbn = &hb_lds[256];
  float hs0 = 0.f, hs1 = 0.f;  // fp32 self-copy (mt=0 waves authoritative)

  for (int ct = 0; ct < 16; ++ct) {
    // S1: rv0 = h @ rkr (both mt waves duplicate).  Split-K 2 chains of 4.
    f32x4 z = (f32x4){0.f,0.f,0.f,0.f};
    f32x4 a0a = z, a0b = z, a1a = z, a1b = z;
    #pragma unroll
    for (int kt = 0; kt < 4; ++kt) {
      bf16x8 hf = *(const bf16x8*)&hbc[kt * 32 + quad * 8];
      a0a = mfma16(hf, fr[0][kt], a0a);
      a1a = mfma16(hf, fr[1][kt], a1a);
    }
    #pragma unroll
    for (int kt = 4; kt < 8; ++kt) {
      bf16x8 hf = *(const bf16x8*)&hbc[kt * 32 + quad * 8];
      a0b = mfma16(hf, fr[0][kt], a0b);
      a1b = mfma16(hf, fr[1][kt], a1b);
    }
    f32x4 ac0 = a0a + a0b, ac1 = a1a + a1b;
    // rv via intra-wave shuffles (producing wave == consuming wave):
    float rv[8];
    #pragma unroll
    for (int j = 0; j < 8; ++j) {
      int c = quad * 8 + j;
      float v0 = __shfl(ac0[0], c & 15, 64);
      float v1 = __shfl(ac1[0], c & 15, 64);
      rv[j] = (c < 16) ? v0 : v1;
    }
    // S2: rh A-frag (kt=wg) for OWN M-tile only
    {
      bf16x8 aW = *(const bf16x8*)&hbc[wg * 32 + quad * 8];
      bf16x8 rh;
      #pragma unroll
      for (int j = 0; j < 8; ++j)
        rh[j] = (__bf16)(sigmoid_f((float)xf_c[j] + rv[j]) * (float)aW[j]);
      *(bf16x8*)&fragbuf[mt * 4096 + (wg * 64 + lane) * 8] = rh;
    }
    ldsbar();  // bar_B: fragbuf visible
    // prefetch next chunk's xr/xh (own mt; consumed next iteration)
    bf16x8 xf_n;
    bf16x4 xh_n[2];
    {
      int ctn = (ct + 1) & 15;
      xf_n = *(const bf16x8*)(xrb + (size_t)(2 * ctn + mt) * 4096 + ((size_t)wg * 64 + lane) * 8);
      #pragma unroll
      for (int nt = 0; nt < 2; ++nt)
        xh_n[nt] = *(const bf16x4*)(xhb + ((size_t)(2 * ctn + mt) * 16 + wg * 2 + nt) * 256 + lane * 4);
    }
    // S3: HH = rh @ rkh for OWN M-tile (2 chains of 8)
    f32x4 aH0 = z, aH1 = z;
    #pragma unroll
    for (int kt = 0; kt < 8; ++kt) {
      bf16x8 f0 = *(const bf16x8*)&rkh_lds[(((size_t)kt * 16 + wg * 2)     * 64 + lane) * 8];
      bf16x8 f1 = *(const bf16x8*)&rkh_lds[(((size_t)kt * 16 + wg * 2 + 1) * 64 + lane) * 8];
      bf16x8 a = *(const bf16x8*)&fragbuf[mt * 4096 + (kt * 64 + lane) * 8];
      aH0 = mfma16(a, f0, aH0);
      aH1 = mfma16(a, f1, aH1);
    }
    // blend own mt: partial = sum_{s in own half} aw[s]*tanh(xh+HH)[s]
    const float* awp = &aw_lds[ct * 32];
    f32x4 wq = *(const f32x4*)&awp[mt * 16 + quad * 4];
    float Pt = pt_lds[ct];
    float part0 = 0.f, part1 = 0.f;
    #pragma unroll
    for (int r = 0; r < 4; ++r) {
      part0 += wq[r] * tanh_f((float)xh_c[0][r] + aH0[r]);
      part1 += wq[r] * tanh_f((float)xh_c[1][r] + aH1[r]);
    }
    part0 += __shfl_xor(part0, 16, 64); part0 += __shfl_xor(part0, 32, 64);
    part1 += __shfl_xor(part1, 16, 64); part1 += __shfl_xor(part1, 32, 64);
    if (mt == 1) {           // wave-uniform branch
      if (quad == 0) {
        h1part[wg * 32 + col]      = part0;
        h1part[wg * 32 + 16 + col] = part1;
      }
    }
    ldsbar();  // bar_C: h1part visible
    if (mt == 0) {           // wave-uniform branch
      float hn0 = Pt * hs0 + part0 + h1part[wg * 32 + col];
      float hn1 = Pt * hs1 + part1 + h1part[wg * 32 + 16 + col];
      hs0 = hn0; hs1 = hn1;
      if (quad == 0) {
        hbn[wg * 32 + col]      = (__bf16)hn0;
        hbn[wg * 32 + 16 + col] = (__bf16)hn1;
      }
    }
    ldsbar();  // bar_D: new h visible; fragbuf free
    { bf16_t* t = hbc; hbc = hbn; hbn = t; }
    xf_c = xf_n;
    xh_c[0] = xh_n[0];
    xh_c[1] = xh_n[1];
  }
  // hbc now holds the episode vector (bf16)

  // phase D: memory = relu([mem, episode, q] @ Wm + bm); wave w -> nt=w
  {
    f32x4 am_a = (f32x4){0.f,0.f,0.f,0.f}, am_b = am_a;
    const bf16_t* wmb = ws + E_WMF;
    #pragma unroll
    for (int kt = 0; kt < 24; ++kt) {
      bf16x8 a;
      if (kt >= 8 && kt < 16) {           // episode: already bf16, broadcast read
        a = *(const bf16x8*)&hbc[(kt - 8) * 32 + quad * 8];
      } else {
        const float* sv = (kt < 8) ? &mem_lds[kt * 32] : &q_lds[(kt - 16) * 32];
        const f32x4* vp = (const f32x4*)&sv[quad * 8];
        f32x4 va = vp[0], vb = vp[1];
        #pragma unroll
        for (int j = 0; j < 4; ++j) { a[j] = (__bf16)va[j]; a[4 + j] = (__bf16)vb[j]; }
      }
      bf16x8 bf = *(const bf16x8*)(wmb + (((size_t)kt * 16 + w) * 64 + lane) * 8);
      if (kt & 1) am_b = mfma16(a, bf, am_b);
      else        am_a = mfma16(a, bf, am_a);
    }
    if (quad == 0) {
      int v = w * 16 + col;
      float r = fmaxf(am_a[0] + am_b[0] + bm_lds[v], 0.f);
      mem_ws[(size_t)b * 256 + v] = r;
      if (last) out[(size_t)b * 256 + v] = r;
    }
  }
}

extern "C" void kernel_launch(void* const* d_in, const int* in_sizes, int n_in,
                              void* d_out, int out_size, void* d_ws, size_t ws_size,
                              hipStream_t stream) {
  (void)in_sizes; (void)n_in; (void)out_size; (void)ws_size;
  const float* facts    = (const float*)d_in[0];
  const float* question = (const float*)d_in[1];
  const float* W1       = (const float*)d_in[2];
  const float* b1       = (const float*)d_in[3];
  const float* W2       = (const float*)d_in[4];
  const float* b2       = (const float*)d_in[5];
  const float* gru_k    = (const float*)d_in[6];
  const float* gru_rk   = (const float*)d_in[7];
  const float* gru_b    = (const float*)d_in[8];
  const float* Wm       = (const float*)d_in[9];
  const float* bm       = (const float*)d_in[10];
  bf16_t* ws = (bf16_t*)d_ws;
  float* fws = (float*)(ws + E_END);
  float* scores_ws = fws + F_SCORES;
  float* mem_ws    = fws + F_MEM;
  float* pfix_ws   = fws + F_PFIX;
  float* out = (float*)d_out;

  prep_weights<<<2048, 256, 0, stream>>>(gru_k, gru_rk, W1, Wm, ws);
  xproj_kernel<<<dim3(128, 8), 512, 0, stream>>>(facts, question, gru_b, ws, mem_ws);
  // ep0: mem==question, scores come out of the fixed kernel directly
  scores_fixed_kernel<<<dim3(128, 8), 256, 0, stream>>>(question, b1, W2, b2, ws, pfix_ws, scores_ws);
  for (int ep = 0; ep < 3; ++ep) {
    scan_kernel<<<128, 1024, 0, stream>>>(question, bm, ws, scores_ws, mem_ws, out, ep == 2);
    if (ep < 2)
      scores_kernel<<<dim3(128, 8), 256, 0, stream>>>(W2, b2, ws, mem_ws, pfix_ws, scores_ws);
  }
}

// Round 9
// 392.211 us; speedup vs baseline: 1.7593x; 1.0236x over previous
//
#include <hip/hip_runtime.h>
#include <cstdint>
#include <cstddef>

// ---------------------------------------------------------------------------
// Episodic memory module (DMN) on MI355X — round 16.
//
// R15 post-mortem: launch_bounds(1024,4) hint IGNORED — VGPR stayed 64,
// FETCH stayed 38.7MB (fr streamed from L2 every chunk).  The backend
// targets max theoretical occupancy from registers (8 waves/EU @ 64 VGPR)
// and sinks the fr loads into the loop, even though LDS 151.5KB already
// caps residency at 1 WG/CU (16 waves = 4/EU) — the thrift buys nothing.
//
// R16: two explicit knobs on scan:
//  (1) amdgpu_waves_per_eu(4,4): max waves/EU = 4 -> no benefit below 128
//      VGPR, so the scheduler stops dieting;
//  (2) opaque asm pin on fr after the pre-loop load (asm "+v" on each
//      fragment): loads cannot be sunk into the loop; values must stay
//      register-resident (live ~118 < 128) or spill (tripwire WRITE_SIZE).
// Predictions: scan VGPR 64->~120, FETCH 38.7->~6MB, dur 66->~45us.
// Tripwire: WRITE_SIZE ~2MB (no scratch); else revert pin -> plan C
// (rkr in LDS, rkh streamed with early-issue cover).
// ---------------------------------------------------------------------------

typedef __bf16 bf16_t;
typedef __attribute__((ext_vector_type(8))) __bf16 bf16x8;
typedef __attribute__((ext_vector_type(4))) __bf16 bf16x4;
typedef __attribute__((ext_vector_type(4))) float f32x4;

static __device__ __forceinline__ f32x4 mfma16(bf16x8 a, bf16x8 b, f32x4 c) {
  return __builtin_amdgcn_mfma_f32_16x16x32_bf16(a, b, c, 0, 0, 0);
}
static __device__ __forceinline__ float fast_rcp(float x) { return __builtin_amdgcn_rcpf(x); }
static __device__ __forceinline__ float sigmoid_f(float x) {
  return fast_rcp(1.f + exp2f(-1.44269504f * x));
}
static __device__ __forceinline__ float tanh_f(float x) {
  float e = exp2f(2.88539008f * x);
  return 1.f - 2.f * fast_rcp(e + 1.f);
}
static __device__ __forceinline__ unsigned short f2bf(float x) {
  __bf16 h = (__bf16)x;
  return __builtin_bit_cast(unsigned short, h);
}
// Workgroup barrier WITHOUT the vmcnt(0) drain __syncthreads() carries.
// All call sites are in wave-uniform control flow.
static __device__ __forceinline__ void ldsbar() {
  asm volatile("s_waitcnt lgkmcnt(0)\n\ts_barrier" ::: "memory");
}
// Opaque pin: value becomes an asm output — cannot be rematerialized or its
// defining load sunk past this point.  Zero instructions emitted.
static __device__ __forceinline__ void pin_frag(bf16x8& v) {
  f32x4 t = __builtin_bit_cast(f32x4, v);
  asm volatile("" : "+v"(t));
  v = __builtin_bit_cast(bf16x8, t);
}

// ws layout (bf16 element offsets).  B-fragment layout for a K x N matrix:
// elem(k,n) at ((kt*NT + nt)*64 + lane)*8 + j, kt=k/32, nt=n/16,
// lane=((k%32)/8)*16 + (n%16), j=k%8.
static constexpr size_t E_GRUK  = 0;                            // K=256 N=512
static constexpr size_t E_RKR   = 131072;                       // K=256 N=256
static constexpr size_t E_RKH   = 196608;
static constexpr size_t E_W1F   = 262144;                       // K=1024 N=64
static constexpr size_t E_WMF   = 327680;                       // K=768 N=256
static constexpr size_t E_XR    = 524288;                       // + b*131072 (A-frag)
static constexpr size_t E_XHC   = E_XR  + (size_t)128 * 131072; // + b*131072 (C order)
static constexpr size_t E_FACTS = E_XHC + (size_t)128 * 131072; // + b*131072 (A-frag)
static constexpr size_t E_END   = E_FACTS + (size_t)128 * 131072;
static constexpr size_t F_SCORES = 0;
static constexpr size_t F_MEM    = 65536;
static constexpr size_t F_PFIX   = 131072;   // 128*32*4*64 f32x4 = 4M floats

__global__ void prep_weights(const float* __restrict__ gru_k,
                             const float* __restrict__ gru_rk,
                             const float* __restrict__ W1,
                             const float* __restrict__ Wm,
                             bf16_t* __restrict__ ws) {
  size_t idx = (size_t)blockIdx.x * 256 + threadIdx.x;
  if (idx >= 524288) return;
  size_t local; int NT, which;
  if (idx < 131072)      { local = idx;          NT = 32; which = 0; }
  else if (idx < 196608) { local = idx - 131072; NT = 16; which = 1; }
  else if (idx < 262144) { local = idx - 196608; NT = 16; which = 2; }
  else if (idx < 327680) { local = idx - 262144; NT = 4;  which = 3; }
  else                   { local = idx - 327680; NT = 16; which = 4; }
  int j    = (int)(local & 7);
  int lane = (int)((local >> 3) & 63);
  size_t rem = local >> 9;
  int nt = (int)(rem % NT);
  int kt = (int)(rem / NT);
  int k = kt * 32 + (lane >> 4) * 8 + j;
  int n = nt * 16 + (lane & 15);
  float v;
  switch (which) {
    case 0:  v = gru_k[(size_t)k * 768 + 256 + n]; break;
    case 1:  v = gru_rk[(size_t)k * 768 + 256 + n]; break;
    case 2:  v = gru_rk[(size_t)k * 768 + 512 + n]; break;
    case 3:  v = (n < 50) ? W1[(size_t)k * 50 + n] : 0.f; break;
    default: v = Wm[(size_t)k * 256 + n]; break;
  }
  ws[idx] = (__bf16)v;
}

// ------------------------------- kernel A ----------------------------------
// x_proj = facts[b] @ gru_k[:,U:3U] + bias; also persists facts bf16 A-frags.
// grid (b=128, s=8), 512 threads (8 waves, nt=4/wave).  WG does Mt in
// [4s,4s+4) as 2 pair-iterations; each gk fragment feeds 2 A-tiles.
// (512,4): R8-proven config — VGPR 64, no spills, 66us.  (512,8) spilled.
__global__ __launch_bounds__(512, 4)
void xproj_kernel(const float* __restrict__ facts,
                  const float* __restrict__ question,
                  const float* __restrict__ gru_bg,
                  bf16_t* __restrict__ ws,
                  float* __restrict__ mem_ws) {
  const int b = blockIdx.x, s = blockIdx.y;
  const int tid = threadIdx.x, w = tid >> 6, lane = tid & 63;
  const int quad = lane >> 4, col = lane & 15;
  __shared__ float grub[512];
  __shared__ bf16_t fragbuf[8192];   // 2 tiles; logical unit u at u^kt (swizzled)
  __shared__ bf16_t xrtrans[8192];   // 2 tiles; logical unit u at u^((u>>4)&3)
  grub[tid] = gru_bg[256 + tid];     // [0,256)=xr bias, [256,512)=xh bias
  if (s == 0 && tid < 256) mem_ws[b * 256 + tid] = question[(size_t)b * 256 + tid];
  __syncthreads();

  bf16_t* xr_ws = ws + E_XR   + (size_t)b * 131072;
  bf16_t* xh_ws = ws + E_XHC  + (size_t)b * 131072;
  bf16_t* ff_ws = ws + E_FACTS + (size_t)b * 131072;
  const bf16_t* gbase = ws + E_GRUK;
  // staging ownership: 512 threads cover 2 tiles x 16 rows x 16 col-segs
  const int tile = tid >> 8, row = (tid >> 4) & 15, cseg = tid & 15;

  // this thread's two swizzled fragbuf deposit units (constant across iters)
  int wunit[2];
  #pragma unroll
  for (int half = 0; half < 2; ++half) {
    int u0 = cseg * 16 + half * 8;
    int kt = u0 >> 5, qk = (u0 >> 3) & 3;
    int u = kt * 64 + qk * 16 + row;
    wunit[half] = tile * 512 + (u ^ kt);
  }

  for (int it = 0; it < 2; ++it) {
    const int Mt0 = s * 4 + 2 * it;
    // stage this thread's 16 facts floats (one tile each; 512 thr = 2 tiles)
    float v[16];
    {
      const float* src = facts + (((size_t)b * 512) + (Mt0 + tile) * 16 + row) * 256 + cseg * 16;
      #pragma unroll
      for (int i = 0; i < 4; ++i) {
        f32x4 t4 = ((const f32x4*)src)[i];
        v[4*i] = t4[0]; v[4*i+1] = t4[1]; v[4*i+2] = t4[2]; v[4*i+3] = t4[3];
      }
    }
    #pragma unroll
    for (int half = 0; half < 2; ++half) {
      bf16x8 pk;
      #pragma unroll
      for (int j = 0; j < 8; ++j) pk[j] = (__bf16)v[half * 8 + j];
      *(bf16x8*)&fragbuf[wunit[half] * 8] = pk;
    }
    ldsbar();  // bar1: fragbuf visible
    { // persist facts frags for scores (unswizzle -> ws holds logical layout)
      #pragma unroll
      for (int e = 0; e < 2; ++e) {
        int p = 2 * tid + e;
        int t = p >> 9, pu = p & 511;
        int qu = pu ^ (pu >> 6);
        bf16x8 f = *(bf16x8*)&fragbuf[(t * 512 + qu) * 8];
        *(bf16x8*)(ff_ws + (size_t)(Mt0 + t) * 4096 + (size_t)pu * 8) = f;
      }
    }
    // paired MFMA: each gk fragment load feeds BOTH A-tiles; wave owns nt=4
    f32x4 acc[2][4];
    #pragma unroll
    for (int t = 0; t < 2; ++t)
      #pragma unroll
      for (int nt = 0; nt < 4; ++nt) acc[t][nt] = (f32x4){0.f, 0.f, 0.f, 0.f};
    #pragma unroll
    for (int kt = 0; kt < 8; ++kt) {
      int us = (kt * 64 + lane) ^ kt;
      bf16x8 af0 = *(const bf16x8*)&fragbuf[(size_t)us * 8];
      bf16x8 af1 = *(const bf16x8*)&fragbuf[(size_t)(512 + us) * 8];
      #pragma unroll
      for (int nt = 0; nt < 4; ++nt) {
        bf16x8 g = *(const bf16x8*)(gbase + (((size_t)kt * 32 + (w * 4 + nt)) * 64 + lane) * 8);
        acc[0][nt] = mfma16(af0, g, acc[0][nt]);
        acc[1][nt] = mfma16(af1, g, acc[1][nt]);
      }
    }
    // epilogue: waves 0-3 -> xr (transpose via swizzled LDS), 4-7 -> xh
    #pragma unroll
    for (int t = 0; t < 2; ++t)
      #pragma unroll
      for (int nt = 0; nt < 4; ++nt) {
        int o = w * 64 + nt * 16 + col;
        float bias = grub[o];
        if (o < 256) { // wave-uniform: w < 4
          int ktA = o >> 5, qkA = (o >> 3) & 3, j = o & 7;
          #pragma unroll
          for (int r = 0; r < 4; ++r) {
            int u = ktA * 64 + qkA * 16 + (quad * 4 + r);
            int us2 = u ^ ((u >> 4) & 3);
            xrtrans[(t * 512 + us2) * 8 + j] = (__bf16)(acc[t][nt][r] + bias);
          }
        } else {       // wave-uniform: w >= 4
          int ntx = (o >> 4) - 16;
          unsigned short s0 = f2bf(acc[t][nt][0] + bias), s1 = f2bf(acc[t][nt][1] + bias);
          unsigned short s2 = f2bf(acc[t][nt][2] + bias), s3 = f2bf(acc[t][nt][3] + bias);
          uint2 pv;
          pv.x = (unsigned)s0 | ((unsigned)s1 << 16);
          pv.y = (unsigned)s2 | ((unsigned)s3 << 16);
          *(uint2*)(xh_ws + ((size_t)(Mt0 + t) * 16 + ntx) * 256 + lane * 4) = pv;
        }
      }
    ldsbar();  // bar2: xrtrans visible
    { // xr store: read swizzled, write logical (ws layout unchanged for scan)
      #pragma unroll
      for (int e = 0; e < 2; ++e) {
        int p = 2 * tid + e;
        int t = p >> 9, pu = p & 511;
        int qu = pu ^ ((pu >> 4) & 3);
        bf16x8 f = *(bf16x8*)&xrtrans[(t * 512 + qu) * 8];
        *(bf16x8*)(xr_ws + (size_t)(Mt0 + t) * 4096 + (size_t)pu * 8) = f;
      }
    }
    // no bar3: next iteration's bar1 orders xrtrans reads vs next writes.
  }
}

// ---------------------------- kernel B0 (once) -----------------------------
// P_fixed = (f.q)@W1[0:256] + |f-q|@W1[512:768] + b1 for all (b, n, h),
// AND episode-0 scores (mem==question at ep0 so m-frags == q-frags).
// pfix stored in C-frag order (f32x4/lane) as the later-episode acc init.
__global__ __launch_bounds__(256)
void scores_fixed_kernel(const float* __restrict__ question,
                         const float* __restrict__ b1g,
                         const float* __restrict__ W2g,
                         const float* __restrict__ b2g,
                         const bf16_t* __restrict__ ws,
                         float* __restrict__ pfix,
                         float* __restrict__ scores_ws) {
  const int b = blockIdx.x, s = blockIdx.y;
  const int tid = threadIdx.x, w = tid >> 6, lane = tid & 63;
  const int quad = lane >> 4, col = lane & 15;
  __shared__ float q_lds[256], b1_lds[64], W2_lds[64], score_lds[64];
  __shared__ float b2s;
  q_lds[tid] = question[(size_t)b * 256 + tid];
  if (tid < 64) {
    b1_lds[tid] = (tid < 50) ? b1g[tid] : 0.f;
    W2_lds[tid] = (tid < 50) ? W2g[tid] : 0.f;
  }
  if (tid == 0) b2s = b2g[0];
  __syncthreads();
  if (tid < 64) score_lds[tid] = b2s;
  __syncthreads();

  const bf16_t* ffb = ws + E_FACTS + (size_t)b * 131072 + (size_t)s * 4 * 4096;
  const bf16_t* w1b = ws + E_W1F;

  f32x4 accq[4], accm[4];
  #pragma unroll
  for (int mt = 0; mt < 4; ++mt) {
    accq[mt] = (f32x4){0.f, 0.f, 0.f, 0.f};
    accm[mt] = (f32x4){0.f, 0.f, 0.f, 0.f};
  }

  #pragma unroll 2
  for (int kt = 0; kt < 8; ++kt) {
    bf16x8 wf0 = *(const bf16x8*)(w1b + (((size_t)(kt)      * 4 + w) * 64 + lane) * 8);
    bf16x8 wf1 = *(const bf16x8*)(w1b + (((size_t)(8  + kt) * 4 + w) * 64 + lane) * 8);
    bf16x8 wf2 = *(const bf16x8*)(w1b + (((size_t)(16 + kt) * 4 + w) * 64 + lane) * 8);
    bf16x8 wf3 = *(const bf16x8*)(w1b + (((size_t)(24 + kt) * 4 + w) * 64 + lane) * 8);
    const f32x4* qp = (const f32x4*)&q_lds[kt * 32 + quad * 8];
    f32x4 qa = qp[0], qb = qp[1];
    float qv[8] = {qa[0],qa[1],qa[2],qa[3],qb[0],qb[1],qb[2],qb[3]};
    #pragma unroll
    for (int mt = 0; mt < 4; ++mt) {
      bf16x8 f8 = *(const bf16x8*)(ffb + (size_t)mt * 4096 + (kt * 64 + lane) * 8);
      bf16x8 a0, a2;
      #pragma unroll
      for (int j = 0; j < 8; ++j) {
        float fu = (float)f8[j];
        a0[j] = (__bf16)(fu * qv[j]);
        a2[j] = (__bf16)fabsf(fu - qv[j]);
      }
      accq[mt] = mfma16(a0, wf0, accq[mt]);
      accq[mt] = mfma16(a2, wf2, accq[mt]);
      accm[mt] = mfma16(a0, wf1, accm[mt]);
      accm[mt] = mfma16(a2, wf3, accm[mt]);
    }
  }
  int hcol = w * 16 + col;
  float pb1 = b1_lds[hcol], pw2 = W2_lds[hcol];
  f32x4* po = (f32x4*)pfix;
  #pragma unroll
  for (int mt = 0; mt < 4; ++mt) {
    // pfix = q-terms + b1 (the later-episode accumulator seed)
    f32x4 o = accq[mt];
    #pragma unroll
    for (int r = 0; r < 4; ++r) o[r] += pb1;
    po[(((size_t)b * 32 + s * 4 + mt) * 4 + w) * 64 + lane] = o;
    // ep0 score partial: tanh(pfix + m-terms) * W2  (mem==q at ep0)
    float p[4];
    #pragma unroll
    for (int r = 0; r < 4; ++r) p[r] = tanh_f(o[r] + accm[mt][r]) * pw2;
    #pragma unroll
    for (int r = 0; r < 4; ++r) {
      p[r] += __shfl_xor(p[r], 1, 64);
      p[r] += __shfl_xor(p[r], 2, 64);
      p[r] += __shfl_xor(p[r], 4, 64);
      p[r] += __shfl_xor(p[r], 8, 64);
    }
    if (col == 0) {
      #pragma unroll
      for (int r = 0; r < 4; ++r)
        atomicAdd(&score_lds[mt * 16 + quad * 4 + r], p[r]);
    }
  }
  __syncthreads();
  if (tid < 64) scores_ws[(size_t)b * 512 + s * 64 + tid] = score_lds[tid];
}

// ------------------------------- kernel B ----------------------------------
// scores[b, n] for episodes 1,2: m-terms only on top of P_fixed.
// grid (b=128, s=8); WG does rows [64s,64s+64).  (R10-proven, ~34us)
__global__ __launch_bounds__(256)
void scores_kernel(const float* __restrict__ W2g,
                   const float* __restrict__ b2g,
                   const bf16_t* __restrict__ ws,
                   const float* __restrict__ mem_ws,
                   const float* __restrict__ pfix,
                   float* __restrict__ scores_ws) {
  const int b = blockIdx.x, s = blockIdx.y;
  const int tid = threadIdx.x, w = tid >> 6, lane = tid & 63;
  const int quad = lane >> 4, col = lane & 15;
  __shared__ float mem_lds[256], W2_lds[64], score_lds[64];
  __shared__ float b2s;
  mem_lds[tid] = mem_ws[(size_t)b * 256 + tid];
  if (tid < 64) W2_lds[tid] = (tid < 50) ? W2g[tid] : 0.f;
  if (tid == 0) b2s = b2g[0];
  __syncthreads();
  if (tid < 64) score_lds[tid] = b2s;
  __syncthreads();

  const bf16_t* ffb = ws + E_FACTS + (size_t)b * 131072 + (size_t)s * 4 * 4096;
  const bf16_t* w1b = ws + E_W1F;
  const f32x4* pf = (const f32x4*)pfix;

  f32x4 acc[4];
  #pragma unroll
  for (int mt = 0; mt < 4; ++mt)
    acc[mt] = pf[(((size_t)b * 32 + s * 4 + mt) * 4 + w) * 64 + lane];

  #pragma unroll 2
  for (int kt = 0; kt < 8; ++kt) {
    bf16x8 wf1 = *(const bf16x8*)(w1b + (((size_t)(8  + kt) * 4 + w) * 64 + lane) * 8);
    bf16x8 wf3 = *(const bf16x8*)(w1b + (((size_t)(24 + kt) * 4 + w) * 64 + lane) * 8);
    const f32x4* mp = (const f32x4*)&mem_lds[kt * 32 + quad * 8];
    f32x4 ma = mp[0], mb = mp[1];
    float mv[8] = {ma[0],ma[1],ma[2],ma[3],mb[0],mb[1],mb[2],mb[3]};
    #pragma unroll
    for (int mt = 0; mt < 4; ++mt) {
      bf16x8 f8 = *(const bf16x8*)(ffb + (size_t)mt * 4096 + (kt * 64 + lane) * 8);
      bf16x8 a1, a3;
      #pragma unroll
      for (int j = 0; j < 8; ++j) {
        float fu = (float)f8[j];
        a1[j] = (__bf16)(fu * mv[j]);
        a3[j] = (__bf16)fabsf(fu - mv[j]);
      }
      acc[mt] = mfma16(a1, wf1, acc[mt]);
      acc[mt] = mfma16(a3, wf3, acc[mt]);
    }
  }
  int hcol = w * 16 + col;
  float pw2 = W2_lds[hcol];
  #pragma unroll
  for (int mt = 0; mt < 4; ++mt) {
    float p[4];
    #pragma unroll
    for (int r = 0; r < 4; ++r) p[r] = tanh_f(acc[mt][r]) * pw2;
    #pragma unroll
    for (int r = 0; r < 4; ++r) {
      p[r] += __shfl_xor(p[r], 1, 64);
      p[r] += __shfl_xor(p[r], 2, 64);
      p[r] += __shfl_xor(p[r], 4, 64);
      p[r] += __shfl_xor(p[r], 8, 64);
    }
    if (col == 0) {
      #pragma unroll
      for (int r = 0; r < 4; ++r)
        atomicAdd(&score_lds[mt * 16 + quad * 4 + r], p[r]);
    }
  }
  __syncthreads();
  if (tid < 64) scores_ws[(size_t)b * 512 + s * 64 + tid] = score_lds[tid];
}

// ------------------------------- kernel C ----------------------------------
// softmax + chunked-Picard attn-GRU scan (T=32, 16 chunks) + memory update.
// 128 WGs x 1024 threads (16 waves = 4/SIMD).  Wave w: wg=w&7 (cols
// [32wg,32wg+32)), mt=w>>3 (M-tile).  S1 duplicated across the mt pair
// (keeps intra-wave shuffle rv); S2/S3/blend split by mt.  mt=1 blend
// partial -> h1part LDS; 3 barriers/chunk.  h in LDS bf16; fp32 self-term.
// R16: waves_per_eu(4,4) removes the scheduler's 64-VGPR occupancy target
// (LDS already caps at 1 WG/CU); asm pin on fr prevents the loads being
// sunk into the loop (the 33.5MB/dispatch L2 stream).
__global__
__attribute__((amdgpu_flat_work_group_size(1024, 1024), amdgpu_waves_per_eu(4, 4)))
void scan_kernel(const float* __restrict__ question,
                 const float* __restrict__ bmg,
                 const bf16_t* __restrict__ ws,
                 const float* __restrict__ scores_ws,
                 float* __restrict__ mem_ws,
                 float* __restrict__ out,
                 int last) {
  const int b = blockIdx.x;
  const int tid = threadIdx.x, w = tid >> 6, lane = tid & 63;
  const int quad = lane >> 4, col = lane & 15;
  const int wg = w & 7, mt = w >> 3;

  __shared__ bf16_t hb_lds[512];        // bf16 h ping-pong [0,256) / [256,512)
  __shared__ float aw_lds[512], pt_lds[16];
  __shared__ float q_lds[256], mem_lds[256], bm_lds[256], red[16];
  __shared__ float h1part[256];         // mt=1 blend partials
  __shared__ bf16_t fragbuf[8192];      // rh A-frags, 2 M-tiles x 4096
  __shared__ bf16_t rkh_lds[65536];     // rkh B-frags, 128KB, staged once

  // stage rkh frags global->LDS, stride-1 per lane (conflict-free, coalesced)
  // 8192 bf16x8 units / 1024 threads = 8 iterations.
  {
    const bf16x8* srcw = (const bf16x8*)(ws + E_RKH);
    bf16x8* dstw = (bf16x8*)rkh_lds;
    #pragma unroll
    for (int i = 0; i < 8; ++i)
      dstw[(size_t)i * 1024 + tid] = srcw[(size_t)i * 1024 + tid];
  }

  if (tid < 256) {
    q_lds[tid]   = question[(size_t)b * 256 + tid];
    mem_lds[tid] = mem_ws[(size_t)b * 256 + tid];
    bm_lds[tid]  = bmg[tid];
  }
  if (tid < 512) hb_lds[tid] = (__bf16)0.f;

  // softmax over 512 scores: waves 0-7 (tid<512) do the work, barriers global
  float s0 = 0.f, e0 = 0.f;
  if (tid < 512) {
    s0 = scores_ws[(size_t)b * 512 + tid];
    float mx = s0;
    #pragma unroll
    for (int o = 32; o > 0; o >>= 1) mx = fmaxf(mx, __shfl_xor(mx, o, 64));
    if (lane == 0) red[w] = mx;
  }
  __syncthreads();
  if (tid < 512) {
    float gmax = red[0];
    #pragma unroll
    for (int i = 1; i < 8; ++i) gmax = fmaxf(gmax, red[i]);
    e0 = __expf(s0 - gmax);
    float sm = e0;
    #pragma unroll
    for (int o = 32; o > 0; o >>= 1) sm += __shfl_xor(sm, o, 64);
    if (lane == 0) red[8 + w] = sm;
  }
  __syncthreads();
  if (tid < 512) {
    float tot = red[8];
    #pragma unroll
    for (int i = 9; i < 16; ++i) tot += red[i];
    aw_lds[tid] = e0 * fast_rcp(tot);
  }
  ldsbar();
  // per-chunk (T=32) blend weights in place:
  // aw[s] := a_s * prod_{j>s in chunk}(1-a_j),  pt[ct] := prod(1-a) over chunk
  if (tid < 16) {
    float av[32];
    #pragma unroll
    for (int j = 0; j < 32; ++j) av[j] = aw_lds[tid * 32 + j];
    float suf = 1.f;
    #pragma unroll
    for (int j = 31; j >= 0; --j) {
      aw_lds[tid * 32 + j] = av[j] * suf;
      suf *= (1.f - av[j]);
    }
    pt_lds[tid] = suf;
  }
  ldsbar();  // also covers rkh_lds staging visibility (lgkmcnt drains ds_writes)

  // S1 recurrence weights: wg owns out cols [32wg, 32wg+32); 64 VGPR.
  // Duplicated across the mt pair (both waves run S1).  Pinned in registers
  // via opaque asm so the loads cannot be sunk into the chunk loop.
  const bf16_t* xrb = ws + E_XR  + (size_t)b * 131072;
  const bf16_t* xhb = ws + E_XHC + (size_t)b * 131072;
  bf16x8 fr[2][8];
  {
    const bf16_t* rb = ws + E_RKR;
    #pragma unroll
    for (int nt = 0; nt < 2; ++nt)
      #pragma unroll
      for (int kt = 0; kt < 8; ++kt) {
        size_t off = (((size_t)kt * 16 + (wg * 2 + nt)) * 64 + lane) * 8;
        fr[nt][kt] = *(const bf16x8*)(rb + off);
      }
    #pragma unroll
    for (int nt = 0; nt < 2; ++nt)
      #pragma unroll
      for (int kt = 0; kt < 8; ++kt)
        pin_frag(fr[nt][kt]);
  }
  // chunk-0 xr (A-frag, kt=wg, own mt) and xh (C order, 2 nt, own mt)
  bf16x8 xf_c;
  bf16x4 xh_c[2];
  xf_c = *(const bf16x8*)(xrb + (size_t)mt * 4096 + ((size_t)wg * 64 + lane) * 8);
  #pragma unroll
  for (int nt = 0; nt < 2; ++nt)
    xh_c[nt] = *(const bf16x4*)(xhb + ((size_t)mt * 16 + wg * 2 + nt) * 256 + lane * 4);

  bf16_t* hbc = &hb_lds[0];
  bf16_t* hbn = &hb_lds[256];
  float hs0 = 0.f, hs1 = 0.f;  // fp32 self-copy (mt=0 waves authoritative)

  for (int ct = 0; ct < 16; ++ct) {
    // S1: rv0 = h @ rkr (both mt waves duplicate).  Split-K 2 chains of 4.
    f32x4 z = (f32x4){0.f,0.f,0.f,0.f};
    f32x4 a0a = z, a0b = z, a1a = z, a1b = z;
    #pragma unroll
    for (int kt = 0; kt < 4; ++kt) {
      bf16x8 hf = *(const bf16x8*)&hbc[kt * 32 + quad * 8];
      a0a = mfma16(hf, fr[0][kt], a0a);
      a1a = mfma16(hf, fr[1][kt], a1a);
    }
    #pragma unroll
    for (int kt = 4; kt < 8; ++kt) {
      bf16x8 hf = *(const bf16x8*)&hbc[kt * 32 + quad * 8];
      a0b = mfma16(hf, fr[0][kt], a0b);
      a1b = mfma16(hf, fr[1][kt], a1b);
    }
    f32x4 ac0 = a0a + a0b, ac1 = a1a + a1b;
    // rv via intra-wave shuffles (producing wave == consuming wave):
    float rv[8];
    #pragma unroll
    for (int j = 0; j < 8; ++j) {
      int c = quad * 8 + j;
      float v0 = __shfl(ac0[0], c & 15, 64);
      float v1 = __shfl(ac1[0], c & 15, 64);
      rv[j] = (c < 16) ? v0 : v1;
    }
    // S2: rh A-frag (kt=wg) for OWN M-tile only
    {
      bf16x8 aW = *(const bf16x8*)&hbc[wg * 32 + quad * 8];
      bf16x8 rh;
      #pragma unroll
      for (int j = 0; j < 8; ++j)
        rh[j] = (__bf16)(sigmoid_f((float)xf_c[j] + rv[j]) * (float)aW[j]);
      *(bf16x8*)&fragbuf[mt * 4096 + (wg * 64 + lane) * 8] = rh;
    }
    ldsbar();  // bar_B: fragbuf visible
    // prefetch next chunk's xr/xh (own mt; consumed next iteration)
    bf16x8 xf_n;
    bf16x4 xh_n[2];
    {
      int ctn = (ct + 1) & 15;
      xf_n = *(const bf16x8*)(xrb + (size_t)(2 * ctn + mt) * 4096 + ((size_t)wg * 64 + lane) * 8);
      #pragma unroll
      for (int nt = 0; nt < 2; ++nt)
        xh_n[nt] = *(const bf16x4*)(xhb + ((size_t)(2 * ctn + mt) * 16 + wg * 2 + nt) * 256 + lane * 4);
    }
    // S3: HH = rh @ rkh for OWN M-tile (2 chains of 8)
    f32x4 aH0 = z, aH1 = z;
    #pragma unroll
    for (int kt = 0; kt < 8; ++kt) {
      bf16x8 f0 = *(const bf16x8*)&rkh_lds[(((size_t)kt * 16 + wg * 2)     * 64 + lane) * 8];
      bf16x8 f1 = *(const bf16x8*)&rkh_lds[(((size_t)kt * 16 + wg * 2 + 1) * 64 + lane) * 8];
      bf16x8 a = *(const bf16x8*)&fragbuf[mt * 4096 + (kt * 64 + lane) * 8];
      aH0 = mfma16(a, f0, aH0);
      aH1 = mfma16(a, f1, aH1);
    }
    // blend own mt: partial = sum_{s in own half} aw[s]*tanh(xh+HH)[s]
    const float* awp = &aw_lds[ct * 32];
    f32x4 wq = *(const f32x4*)&awp[mt * 16 + quad * 4];
    float Pt = pt_lds[ct];
    float part0 = 0.f, part1 = 0.f;
    #pragma unroll
    for (int r = 0; r < 4; ++r) {
      part0 += wq[r] * tanh_f((float)xh_c[0][r] + aH0[r]);
      part1 += wq[r] * tanh_f((float)xh_c[1][r] + aH1[r]);
    }
    part0 += __shfl_xor(part0, 16, 64); part0 += __shfl_xor(part0, 32, 64);
    part1 += __shfl_xor(part1, 16, 64); part1 += __shfl_xor(part1, 32, 64);
    if (mt == 1) {           // wave-uniform branch
      if (quad == 0) {
        h1part[wg * 32 + col]      = part0;
        h1part[wg * 32 + 16 + col] = part1;
      }
    }
    ldsbar();  // bar_C: h1part visible
    if (mt == 0) {           // wave-uniform branch
      float hn0 = Pt * hs0 + part0 + h1part[wg * 32 + col];
      float hn1 = Pt * hs1 + part1 + h1part[wg * 32 + 16 + col];
      hs0 = hn0; hs1 = hn1;
      if (quad == 0) {
        hbn[wg * 32 + col]      = (__bf16)hn0;
        hbn[wg * 32 + 16 + col] = (__bf16)hn1;
      }
    }
    ldsbar();  // bar_D: new h visible; fragbuf free
    { bf16_t* t = hbc; hbc = hbn; hbn = t; }
    xf_c = xf_n;
    xh_c[0] = xh_n[0];
    xh_c[1] = xh_n[1];
  }
  // hbc now holds the episode vector (bf16)

  // phase D: memory = relu([mem, episode, q] @ Wm + bm); wave w -> nt=w
  {
    f32x4 am_a = (f32x4){0.f,0.f,0.f,0.f}, am_b = am_a;
    const bf16_t* wmb = ws + E_WMF;
    #pragma unroll
    for (int kt = 0; kt < 24; ++kt) {
      bf16x8 a;
      if (kt >= 8 && kt < 16) {           // episode: already bf16, broadcast read
        a = *(const bf16x8*)&hbc[(kt - 8) * 32 + quad * 8];
      } else {
        const float* sv = (kt < 8) ? &mem_lds[kt * 32] : &q_lds[(kt - 16) * 32];
        const f32x4* vp = (const f32x4*)&sv[quad * 8];
        f32x4 va = vp[0], vb = vp[1];
        #pragma unroll
        for (int j = 0; j < 4; ++j) { a[j] = (__bf16)va[j]; a[4 + j] = (__bf16)vb[j]; }
      }
      bf16x8 bf = *(const bf16x8*)(wmb + (((size_t)kt * 16 + w) * 64 + lane) * 8);
      if (kt & 1) am_b = mfma16(a, bf, am_b);
      else        am_a = mfma16(a, bf, am_a);
    }
    if (quad == 0) {
      int v = w * 16 + col;
      float r = fmaxf(am_a[0] + am_b[0] + bm_lds[v], 0.f);
      mem_ws[(size_t)b * 256 + v] = r;
      if (last) out[(size_t)b * 256 + v] = r;
    }
  }
}

extern "C" void kernel_launch(void* const* d_in, const int* in_sizes, int n_in,
                              void* d_out, int out_size, void* d_ws, size_t ws_size,
                              hipStream_t stream) {
  (void)in_sizes; (void)n_in; (void)out_size; (void)ws_size;
  const float* facts    = (const float*)d_in[0];
  const float* question = (const float*)d_in[1];
  const float* W1       = (const float*)d_in[2];
  const float* b1       = (const float*)d_in[3];
  const float* W2       = (const float*)d_in[4];
  const float* b2       = (const float*)d_in[5];
  const float* gru_k    = (const float*)d_in[6];
  const float* gru_rk   = (const float*)d_in[7];
  const float* gru_b    = (const float*)d_in[8];
  const float* Wm       = (const float*)d_in[9];
  const float* bm       = (const float*)d_in[10];
  bf16_t* ws = (bf16_t*)d_ws;
  float* fws = (float*)(ws + E_END);
  float* scores_ws = fws + F_SCORES;
  float* mem_ws    = fws + F_MEM;
  float* pfix_ws   = fws + F_PFIX;
  float* out = (float*)d_out;

  prep_weights<<<2048, 256, 0, stream>>>(gru_k, gru_rk, W1, Wm, ws);
  xproj_kernel<<<dim3(128, 8), 512, 0, stream>>>(facts, question, gru_b, ws, mem_ws);
  // ep0: mem==question, scores come out of the fixed kernel directly
  scores_fixed_kernel<<<dim3(128, 8), 256, 0, stream>>>(question, b1, W2, b2, ws, pfix_ws, scores_ws);
  for (int ep = 0; ep < 3; ++ep) {
    scan_kernel<<<128, 1024, 0, stream>>>(question, bm, ws, scores_ws, mem_ws, out, ep == 2);
    if (ep < 2)
      scores_kernel<<<dim3(128, 8), 256, 0, stream>>>(W2, b2, ws, mem_ws, pfix_ws, scores_ws);
  }
}